// Round 1
// baseline (1276.790 us; speedup 1.0000x reference)
//
#include <hip/hip_runtime.h>

#define NV 50257
#define NE 512
#define NH 1024
#define NB 1024
#define TSTEPS 10

// ---------------------------------------------------------------------------
// Kernel 0: emb[b,e] = emb_table[tok[b], e] * mask_emb[b,e]
// ---------------------------------------------------------------------------
__global__ void embed_kernel(const int* __restrict__ tok,
                             const float* __restrict__ table,
                             const float* __restrict__ mask,
                             float* __restrict__ emb) {
    int i = blockIdx.x * blockDim.x + threadIdx.x;   // float4 index
    const int n4 = NB * NE / 4;
    if (i >= n4) return;
    int b = i / (NE / 4);
    int c = i % (NE / 4);
    const float4* trow = (const float4*)(table + (size_t)tok[b] * NE);
    float4 t = trow[c];
    float4 m = ((const float4*)mask)[i];
    float4 o;
    o.x = t.x * m.x; o.y = t.y * m.y; o.z = t.z * m.z; o.w = t.w * m.w;
    ((float4*)emb)[i] = o;
}

// ---------------------------------------------------------------------------
// Kernel 2: LIF recurrence per (b,h). spike counts folded with mask_lif.
// hsum[b,h] = mask_lif[b,h] * sum_t spike_t[b,h]
// ---------------------------------------------------------------------------
__global__ void lif_kernel(const float* __restrict__ delta1,
                           const float* __restrict__ hidden,
                           const float* __restrict__ mask_lif,
                           const float* __restrict__ thr_p,
                           const float* __restrict__ leak_p,
                           float* __restrict__ hsum) {
    int i = blockIdx.x * blockDim.x + threadIdx.x;
    if (i >= NB * NH) return;
    const float thr = thr_p[0];
    const float leak = leak_p[0];
    float d = delta1[i];
    float m = hidden[i];
    float cnt = 0.0f;
#pragma unroll
    for (int t = 0; t < TSTEPS; ++t) {
        float mem = leak * m + d;
        float s = ((mem / thr - 1.0f) > 0.0f) ? 1.0f : 0.0f;
        m = mem - thr * s;      // soft reset
        cnt += s;
    }
    hsum[i] = cnt * mask_lif[i];
}

// ---------------------------------------------------------------------------
// Tiled fp32 NT GEMM: C[m,n] = sum_k A[m,k]*B[n,k] + bias[n]*bias_scale
// A: [M,K] row-major, B: [N,K] row-major. BM=BN=128, BK=16, 256 threads,
// 8x8 micro-tile per thread (cols as two groups of 4 for float4 stores).
// Requires M % 128 == 0, K % 16 == 0. N edge guarded.
// ---------------------------------------------------------------------------
#define BM 128
#define BN 128
#define BK 16

__global__ __launch_bounds__(256)
void gemm_nt(const float* __restrict__ A, const float* __restrict__ Bm,
             const float* __restrict__ bias, float bias_scale,
             float* __restrict__ C, int M, int N, int K) {
    __shared__ float As[BK][BM + 4];
    __shared__ float Bs[BK][BN + 4];

    const int tid = threadIdx.x;
    const int bm = blockIdx.y * BM;
    const int bn = blockIdx.x * BN;
    const int tx = tid & 15;       // 16 cols of threads
    const int ty = tid >> 4;       // 16 rows of threads
    const int tm = ty * 8;         // 8 output rows per thread
    const int tn0 = tx * 4;        // col group 0
    const int tn1 = 64 + tx * 4;   // col group 1

    float acc[8][8];
#pragma unroll
    for (int i = 0; i < 8; ++i)
#pragma unroll
        for (int j = 0; j < 8; ++j) acc[i][j] = 0.0f;

    constexpr int LDA4 = BK / 4;   // float4 per tile row

    for (int k0 = 0; k0 < K; k0 += BK) {
        // stage A tile (transpose into As[k][m])
#pragma unroll
        for (int idx = tid; idx < BM * LDA4; idx += 256) {
            int m = idx / LDA4, c = idx % LDA4;
            float4 v = *(const float4*)(A + (size_t)(bm + m) * K + k0 + c * 4);
            As[c * 4 + 0][m] = v.x;
            As[c * 4 + 1][m] = v.y;
            As[c * 4 + 2][m] = v.z;
            As[c * 4 + 3][m] = v.w;
        }
        // stage B tile (transpose into Bs[k][n]); guard N edge
#pragma unroll
        for (int idx = tid; idx < BN * LDA4; idx += 256) {
            int n = idx / LDA4, c = idx % LDA4;
            float4 v = make_float4(0.f, 0.f, 0.f, 0.f);
            int gn = bn + n;
            if (gn < N) v = *(const float4*)(Bm + (size_t)gn * K + k0 + c * 4);
            Bs[c * 4 + 0][n] = v.x;
            Bs[c * 4 + 1][n] = v.y;
            Bs[c * 4 + 2][n] = v.z;
            Bs[c * 4 + 3][n] = v.w;
        }
        __syncthreads();

#pragma unroll
        for (int k = 0; k < BK; ++k) {
            float4 a0 = *(const float4*)&As[k][tm];
            float4 a1 = *(const float4*)&As[k][tm + 4];
            float4 b0 = *(const float4*)&Bs[k][tn0];
            float4 b1 = *(const float4*)&Bs[k][tn1];
            float a[8] = {a0.x, a0.y, a0.z, a0.w, a1.x, a1.y, a1.z, a1.w};
            float bb[8] = {b0.x, b0.y, b0.z, b0.w, b1.x, b1.y, b1.z, b1.w};
#pragma unroll
            for (int i = 0; i < 8; ++i)
#pragma unroll
                for (int j = 0; j < 8; ++j)
                    acc[i][j] = fmaf(a[i], bb[j], acc[i][j]);
        }
        __syncthreads();
    }

    // epilogue: add bias*scale, store
    if (bn + BN <= N) {
        float4 c0 = *(const float4*)&bias[bn + tn0];
        float4 c1 = *(const float4*)&bias[bn + tn1];
        c0.x *= bias_scale; c0.y *= bias_scale; c0.z *= bias_scale; c0.w *= bias_scale;
        c1.x *= bias_scale; c1.y *= bias_scale; c1.z *= bias_scale; c1.w *= bias_scale;
#pragma unroll
        for (int i = 0; i < 8; ++i) {
            size_t row = (size_t)(bm + tm + i) * N;
            float4 v0, v1;
            v0.x = acc[i][0] + c0.x; v0.y = acc[i][1] + c0.y;
            v0.z = acc[i][2] + c0.z; v0.w = acc[i][3] + c0.w;
            v1.x = acc[i][4] + c1.x; v1.y = acc[i][5] + c1.y;
            v1.z = acc[i][6] + c1.z; v1.w = acc[i][7] + c1.w;
            *(float4*)(C + row + bn + tn0) = v0;
            *(float4*)(C + row + bn + tn1) = v1;
        }
    } else {
#pragma unroll
        for (int i = 0; i < 8; ++i) {
            size_t row = (size_t)(bm + tm + i) * N;
#pragma unroll
            for (int j = 0; j < 8; ++j) {
                int gn = bn + ((j < 4) ? (tn0 + j) : (tn1 + j - 4));
                if (gn < N)
                    C[row + gn] = acc[i][j] + bias[gn] * bias_scale;
            }
        }
    }
}

// ---------------------------------------------------------------------------
extern "C" void kernel_launch(void* const* d_in, const int* in_sizes, int n_in,
                              void* d_out, int out_size, void* d_ws, size_t ws_size,
                              hipStream_t stream) {
    const int*   tok      = (const int*)  d_in[0];
    const float* hidden   = (const float*)d_in[1];
    const float* table    = (const float*)d_in[2];
    const float* W1       = (const float*)d_in[3];
    const float* b1       = (const float*)d_in[4];
    const float* W2       = (const float*)d_in[5];
    const float* b2       = (const float*)d_in[6];
    const float* fc_W     = (const float*)d_in[7];
    const float* fc_b     = (const float*)d_in[8];
    const float* thr      = (const float*)d_in[9];
    const float* leak     = (const float*)d_in[10];
    const float* mask_emb = (const float*)d_in[11];
    const float* mask_lif = (const float*)d_in[12];

    float* linear = (float*)d_out;                 // [B,V]
    float* outbuf = (float*)d_out + (size_t)NB * NV; // [B,H] (second tuple elem)

    float* ws     = (float*)d_ws;
    float* emb    = ws;                       // B*E
    float* delta1 = ws + (size_t)NB * NE;     // B*H
    float* hsum   = delta1 + (size_t)NB * NH; // B*H

    // 0: embedding gather + dropout mask
    {
        int n4 = NB * NE / 4;
        embed_kernel<<<(n4 + 255) / 256, 256, 0, stream>>>(tok, table, mask_emb, emb);
    }
    // 1: delta1 = emb @ W1^T + b1   (M=B, N=H, K=E)
    {
        dim3 grid(NH / BN, NB / BM);
        gemm_nt<<<grid, 256, 0, stream>>>(emb, W1, b1, 1.0f, delta1, NB, NH, NE);
    }
    // 2: LIF scan -> hsum = mask_lif * sum_t spike_t
    {
        int n = NB * NH;
        lif_kernel<<<(n + 255) / 256, 256, 0, stream>>>(delta1, hidden, mask_lif,
                                                        thr, leak, hsum);
    }
    // 3: out = hsum @ W2^T + 10*b2   (M=B, N=H, K=H) -> second output
    {
        dim3 grid(NH / BN, NB / BM);
        gemm_nt<<<grid, 256, 0, stream>>>(hsum, W2, b2, (float)TSTEPS, outbuf, NB, NH, NH);
    }
    // 4: linear = out @ fc_W^T + fc_b  (M=B, N=V, K=H) -> first output
    {
        dim3 grid((NV + BN - 1) / BN, NB / BM);
        gemm_nt<<<grid, 256, 0, stream>>>(outbuf, fc_W, fc_b, 1.0f, linear, NB, NV, NH);
    }
}

// Round 2
// 737.443 us; speedup vs baseline: 1.7314x; 1.7314x over previous
//
#include <hip/hip_runtime.h>

#define NV 50257
#define NE 512
#define NH 1024
#define NB 1024
#define TSTEPS 10

typedef __bf16 bf16x8 __attribute__((ext_vector_type(8)));
typedef float  f32x4  __attribute__((ext_vector_type(4)));

// ---------------------------------------------------------------------------
// Kernel 0: emb[b,e] = emb_table[tok[b], e] * mask_emb[b,e]
// ---------------------------------------------------------------------------
__global__ void embed_kernel(const int* __restrict__ tok,
                             const float* __restrict__ table,
                             const float* __restrict__ mask,
                             float* __restrict__ emb) {
    int i = blockIdx.x * blockDim.x + threadIdx.x;   // float4 index
    const int n4 = NB * NE / 4;
    if (i >= n4) return;
    int b = i / (NE / 4);
    int c = i % (NE / 4);
    const float4* trow = (const float4*)(table + (size_t)tok[b] * NE);
    float4 t = trow[c];
    float4 m = ((const float4*)mask)[i];
    float4 o;
    o.x = t.x * m.x; o.y = t.y * m.y; o.z = t.z * m.z; o.w = t.w * m.w;
    ((float4*)emb)[i] = o;
}

// ---------------------------------------------------------------------------
// Kernel 2: LIF recurrence per (b,h). hsum = mask_lif * sum_t spike_t
// ---------------------------------------------------------------------------
__global__ void lif_kernel(const float* __restrict__ delta1,
                           const float* __restrict__ hidden,
                           const float* __restrict__ mask_lif,
                           const float* __restrict__ thr_p,
                           const float* __restrict__ leak_p,
                           float* __restrict__ hsum) {
    int i = blockIdx.x * blockDim.x + threadIdx.x;
    if (i >= NB * NH) return;
    const float thr = thr_p[0];
    const float leak = leak_p[0];
    float d = delta1[i];
    float m = hidden[i];
    float cnt = 0.0f;
#pragma unroll
    for (int t = 0; t < TSTEPS; ++t) {
        float mem = leak * m + d;
        float s = ((mem / thr - 1.0f) > 0.0f) ? 1.0f : 0.0f;
        m = mem - thr * s;      // soft reset
        cnt += s;
    }
    hsum[i] = cnt * mask_lif[i];
}

// ---------------------------------------------------------------------------
// split fp32 -> bf16 hi + bf16 lo (truncation; lo captures residual)
// n4 = element count / 4
// ---------------------------------------------------------------------------
__global__ void split4_kernel(const float* __restrict__ x,
                              unsigned short* __restrict__ hi,
                              unsigned short* __restrict__ lo, int n4) {
    int i0 = blockIdx.x * blockDim.x + threadIdx.x;
    int stride = gridDim.x * blockDim.x;
    for (int i = i0; i < n4; i += stride) {
        float4 v = ((const float4*)x)[i];
        float vv[4] = {v.x, v.y, v.z, v.w};
        unsigned short hh[4], ll[4];
#pragma unroll
        for (int j = 0; j < 4; ++j) {
            unsigned u = __float_as_uint(vv[j]);
            unsigned short ht = (unsigned short)(u >> 16);
            float hf = __uint_as_float(((unsigned)ht) << 16);
            float r = vv[j] - hf;
            hh[j] = ht;
            ll[j] = (unsigned short)(__float_as_uint(r) >> 16);
        }
        ushort4 h4, l4;
        h4.x = hh[0]; h4.y = hh[1]; h4.z = hh[2]; h4.w = hh[3];
        l4.x = ll[0]; l4.y = ll[1]; l4.z = ll[2]; l4.w = ll[3];
        ((ushort4*)hi)[i] = h4;
        ((ushort4*)lo)[i] = l4;
    }
}

// ---------------------------------------------------------------------------
// Split-bf16 MFMA GEMM: C[m,n] = sum_k A[m,k]*B[n,k] + bias[n]
// A = Ahi+Alo [M=1024, K=1024] bf16 pair, B = Bhi+Blo [NV, 1024] bf16 pair.
// 3-term: hi*hi + hi*lo + lo*hi (lo*lo dropped, ~2^-16 rel).
// 128x128 tile, BK=32, 256 threads (4 waves, each 64x64 quadrant of 4x4
// 16x16x32 fragments). global_load_lds width-16 staging, linear LDS (m97).
// ---------------------------------------------------------------------------
#define GBM 128
#define GBN 128
#define GBK 32

__global__ __launch_bounds__(256)
void gemm_mfma_split(const unsigned short* __restrict__ Ahi,
                     const unsigned short* __restrict__ Alo,
                     const unsigned short* __restrict__ Bhi,
                     const unsigned short* __restrict__ Blo,
                     const float* __restrict__ bias,
                     float* __restrict__ C) {
    __shared__ unsigned short sA[2 * GBM * GBK];   // [hi | lo], each [128][32]
    __shared__ unsigned short sB[2 * GBN * GBK];

    const int tid = threadIdx.x;
    const int w = tid >> 6;          // wave 0..3
    const int l = tid & 63;
    const int bm = blockIdx.y * GBM;
    const int bn = blockIdx.x * GBN;
    const int wr = (w >> 1) * 64;    // wave quadrant row
    const int wc = (w & 1) * 64;     // wave quadrant col

    const int lr = l & 15;           // fragment row (A) / col (B)
    const int lk = (l >> 4) * 8;     // k offset within BK

    f32x4 acc[4][4];
#pragma unroll
    for (int m = 0; m < 4; ++m)
#pragma unroll
        for (int n = 0; n < 4; ++n)
#pragma unroll
            for (int q = 0; q < 4; ++q) acc[m][n][q] = 0.0f;

    // staging geometry: tile = 8KB = 8 chunks of 1KB (64 lanes x 16B);
    // chunk c covers rows [c*16, c*16+16); lane l -> row c*16 + l/4,
    // col (l&3)*8. Wave w stages chunks w*2 and w*2+1 of each subtile.
    const int c0row = (l >> 2);
    const int ckc = (l & 3) * 8;

    for (int k0 = 0; k0 < NH; k0 += GBK) {
#pragma unroll
        for (int i = 0; i < 2; ++i) {
            const int c = w * 2 + i;
            const int row = c * 16 + c0row;
            const size_t aoff = (size_t)(bm + row) * NH + k0 + ckc;
            int gn = bn + row; if (gn >= NV) gn = NV - 1;   // clamp (store-guarded)
            const size_t boff = (size_t)gn * NH + k0 + ckc;
            __builtin_amdgcn_global_load_lds(Ahi + aoff, &sA[c * 512], 16, 0, 0);
            __builtin_amdgcn_global_load_lds(Alo + aoff, &sA[GBM * GBK + c * 512], 16, 0, 0);
            __builtin_amdgcn_global_load_lds(Bhi + boff, &sB[c * 512], 16, 0, 0);
            __builtin_amdgcn_global_load_lds(Blo + boff, &sB[GBN * GBK + c * 512], 16, 0, 0);
        }
        __syncthreads();

        bf16x8 ahi[4], alo[4], bhi[4], blo[4];
#pragma unroll
        for (int m = 0; m < 4; ++m) {
            const int r = wr + m * 16 + lr;
            ahi[m] = *(const bf16x8*)&sA[r * GBK + lk];
            alo[m] = *(const bf16x8*)&sA[GBM * GBK + r * GBK + lk];
        }
#pragma unroll
        for (int n = 0; n < 4; ++n) {
            const int r = wc + n * 16 + lr;
            bhi[n] = *(const bf16x8*)&sB[r * GBK + lk];
            blo[n] = *(const bf16x8*)&sB[GBN * GBK + r * GBK + lk];
        }

#pragma unroll
        for (int m = 0; m < 4; ++m)
#pragma unroll
            for (int n = 0; n < 4; ++n) {
                acc[m][n] = __builtin_amdgcn_mfma_f32_16x16x32_bf16(ahi[m], bhi[n], acc[m][n], 0, 0, 0);
                acc[m][n] = __builtin_amdgcn_mfma_f32_16x16x32_bf16(ahi[m], blo[n], acc[m][n], 0, 0, 0);
                acc[m][n] = __builtin_amdgcn_mfma_f32_16x16x32_bf16(alo[m], bhi[n], acc[m][n], 0, 0, 0);
            }
        __syncthreads();
    }

    // epilogue: C/D layout col = l&15, row = (l>>4)*4 + reg
    const int lq = (l >> 4) * 4;
#pragma unroll
    for (int n = 0; n < 4; ++n) {
        const int gcol = bn + wc + n * 16 + lr;
        if (gcol >= NV) continue;
        const float bb = bias[gcol];
#pragma unroll
        for (int m = 0; m < 4; ++m) {
            const int grow = bm + wr + m * 16 + lq;
#pragma unroll
            for (int q = 0; q < 4; ++q)
                C[(size_t)(grow + q) * NV + gcol] = acc[m][n][q] + bb;
        }
    }
}

// ---------------------------------------------------------------------------
// fp32 NT GEMM (kernels 1 & 3, and fallback): C = A*B^T + bias*bias_scale
// ---------------------------------------------------------------------------
#define BM 128
#define BN 128
#define BK 16

__global__ __launch_bounds__(256)
void gemm_nt(const float* __restrict__ A, const float* __restrict__ Bm,
             const float* __restrict__ bias, float bias_scale,
             float* __restrict__ C, int M, int N, int K) {
    __shared__ float As[BK][BM + 4];
    __shared__ float Bs[BK][BN + 4];

    const int tid = threadIdx.x;
    const int bm = blockIdx.y * BM;
    const int bn = blockIdx.x * BN;
    const int tx = tid & 15;
    const int ty = tid >> 4;
    const int tm = ty * 8;
    const int tn0 = tx * 4;
    const int tn1 = 64 + tx * 4;

    float acc[8][8];
#pragma unroll
    for (int i = 0; i < 8; ++i)
#pragma unroll
        for (int j = 0; j < 8; ++j) acc[i][j] = 0.0f;

    constexpr int LDA4 = BK / 4;

    for (int k0 = 0; k0 < K; k0 += BK) {
#pragma unroll
        for (int idx = tid; idx < BM * LDA4; idx += 256) {
            int m = idx / LDA4, c = idx % LDA4;
            float4 v = *(const float4*)(A + (size_t)(bm + m) * K + k0 + c * 4);
            As[c * 4 + 0][m] = v.x;
            As[c * 4 + 1][m] = v.y;
            As[c * 4 + 2][m] = v.z;
            As[c * 4 + 3][m] = v.w;
        }
#pragma unroll
        for (int idx = tid; idx < BN * LDA4; idx += 256) {
            int n = idx / LDA4, c = idx % LDA4;
            float4 v = make_float4(0.f, 0.f, 0.f, 0.f);
            int gn = bn + n;
            if (gn < N) v = *(const float4*)(Bm + (size_t)gn * K + k0 + c * 4);
            Bs[c * 4 + 0][n] = v.x;
            Bs[c * 4 + 1][n] = v.y;
            Bs[c * 4 + 2][n] = v.z;
            Bs[c * 4 + 3][n] = v.w;
        }
        __syncthreads();

#pragma unroll
        for (int k = 0; k < BK; ++k) {
            float4 a0 = *(const float4*)&As[k][tm];
            float4 a1 = *(const float4*)&As[k][tm + 4];
            float4 b0 = *(const float4*)&Bs[k][tn0];
            float4 b1 = *(const float4*)&Bs[k][tn1];
            float a[8] = {a0.x, a0.y, a0.z, a0.w, a1.x, a1.y, a1.z, a1.w};
            float bb[8] = {b0.x, b0.y, b0.z, b0.w, b1.x, b1.y, b1.z, b1.w};
#pragma unroll
            for (int i = 0; i < 8; ++i)
#pragma unroll
                for (int j = 0; j < 8; ++j)
                    acc[i][j] = fmaf(a[i], bb[j], acc[i][j]);
        }
        __syncthreads();
    }

    if (bn + BN <= N) {
        float4 c0 = *(const float4*)&bias[bn + tn0];
        float4 c1 = *(const float4*)&bias[bn + tn1];
        c0.x *= bias_scale; c0.y *= bias_scale; c0.z *= bias_scale; c0.w *= bias_scale;
        c1.x *= bias_scale; c1.y *= bias_scale; c1.z *= bias_scale; c1.w *= bias_scale;
#pragma unroll
        for (int i = 0; i < 8; ++i) {
            size_t row = (size_t)(bm + tm + i) * N;
            float4 v0, v1;
            v0.x = acc[i][0] + c0.x; v0.y = acc[i][1] + c0.y;
            v0.z = acc[i][2] + c0.z; v0.w = acc[i][3] + c0.w;
            v1.x = acc[i][4] + c1.x; v1.y = acc[i][5] + c1.y;
            v1.z = acc[i][6] + c1.z; v1.w = acc[i][7] + c1.w;
            *(float4*)(C + row + bn + tn0) = v0;
            *(float4*)(C + row + bn + tn1) = v1;
        }
    } else {
#pragma unroll
        for (int i = 0; i < 8; ++i) {
            size_t row = (size_t)(bm + tm + i) * N;
#pragma unroll
            for (int j = 0; j < 8; ++j) {
                int gn = bn + ((j < 4) ? (tn0 + j) : (tn1 + j - 4));
                if (gn < N)
                    C[row + gn] = acc[i][j] + bias[gn] * bias_scale;
            }
        }
    }
}

// ---------------------------------------------------------------------------
extern "C" void kernel_launch(void* const* d_in, const int* in_sizes, int n_in,
                              void* d_out, int out_size, void* d_ws, size_t ws_size,
                              hipStream_t stream) {
    const int*   tok      = (const int*)  d_in[0];
    const float* hidden   = (const float*)d_in[1];
    const float* table    = (const float*)d_in[2];
    const float* W1       = (const float*)d_in[3];
    const float* b1       = (const float*)d_in[4];
    const float* W2       = (const float*)d_in[5];
    const float* b2       = (const float*)d_in[6];
    const float* fc_W     = (const float*)d_in[7];
    const float* fc_b     = (const float*)d_in[8];
    const float* thr      = (const float*)d_in[9];
    const float* leak     = (const float*)d_in[10];
    const float* mask_emb = (const float*)d_in[11];
    const float* mask_lif = (const float*)d_in[12];

    float* linear = (float*)d_out;                   // [B,V]
    float* outbuf = (float*)d_out + (size_t)NB * NV; // [B,H] (second tuple elem)

    // workspace layout
    char* base = (char*)d_ws;
    float* emb    = (float*)base;                    base += (size_t)NB * NE * 4;
    float* delta1 = (float*)base;                    base += (size_t)NB * NH * 4;
    float* hsum   = (float*)base;                    base += (size_t)NB * NH * 4;
    unsigned short* o_hi = (unsigned short*)base;    base += (size_t)NB * NH * 2;
    unsigned short* o_lo = (unsigned short*)base;    base += (size_t)NB * NH * 2;
    unsigned short* w_hi = (unsigned short*)base;    base += (size_t)NV * NH * 2;
    unsigned short* w_lo = (unsigned short*)base;    base += (size_t)NV * NH * 2;
    const size_t ws_needed = (size_t)(base - (char*)d_ws);
    const bool use_mfma = ws_size >= ws_needed;

    // 0: embedding gather + dropout mask
    {
        int n4 = NB * NE / 4;
        embed_kernel<<<(n4 + 255) / 256, 256, 0, stream>>>(tok, table, mask_emb, emb);
    }
    // 1: delta1 = emb @ W1^T + b1   (M=B, N=H, K=E)
    {
        dim3 grid(NH / BN, NB / BM);
        gemm_nt<<<grid, 256, 0, stream>>>(emb, W1, b1, 1.0f, delta1, NB, NH, NE);
    }
    // 2: LIF scan -> hsum = mask_lif * sum_t spike_t
    {
        int n = NB * NH;
        lif_kernel<<<(n + 255) / 256, 256, 0, stream>>>(delta1, hidden, mask_lif,
                                                        thr, leak, hsum);
    }
    // 3: out = hsum @ W2^T + 10*b2   (M=B, N=H, K=H) -> second output
    {
        dim3 grid(NH / BN, NB / BM);
        gemm_nt<<<grid, 256, 0, stream>>>(hsum, W2, b2, (float)TSTEPS, outbuf, NB, NH, NH);
    }
    // 4: linear = out @ fc_W^T + fc_b  (M=B, N=V, K=H) -> first output
    if (use_mfma) {
        {   // split fc_W and out into bf16 hi/lo
            int n4w = NV * NH / 4;
            split4_kernel<<<2048, 256, 0, stream>>>(fc_W, w_hi, w_lo, n4w);
            int n4o = NB * NH / 4;
            split4_kernel<<<(n4o + 255) / 256, 256, 0, stream>>>(outbuf, o_hi, o_lo, n4o);
        }
        dim3 grid((NV + GBN - 1) / GBN, NB / GBM);
        gemm_mfma_split<<<grid, 256, 0, stream>>>(o_hi, o_lo, w_hi, w_lo, fc_b, linear);
    } else {
        dim3 grid((NV + BN - 1) / BN, NB / BM);
        gemm_nt<<<grid, 256, 0, stream>>>(outbuf, fc_W, fc_b, 1.0f, linear, NB, NV, NH);
    }
}

// Round 4
// 702.866 us; speedup vs baseline: 1.8165x; 1.0492x over previous
//
#include <hip/hip_runtime.h>

#define NV 50257
#define NE 512
#define NH 1024
#define NB 1024
#define TSTEPS 10

typedef __bf16 bf16x8 __attribute__((ext_vector_type(8)));
typedef float  f32x4  __attribute__((ext_vector_type(4)));
typedef unsigned short u16;

// ---------------------------------------------------------------------------
// fp32 -> bf16 hi + bf16 lo (truncation split; hi+lo error ~2^-16 relative)
// ---------------------------------------------------------------------------
__device__ inline void split1(float v, u16& h, u16& l) {
    unsigned u = __float_as_uint(v);
    u16 ht = (u16)(u >> 16);
    float r = v - __uint_as_float(((unsigned)ht) << 16);
    h = ht;
    l = (u16)(__float_as_uint(r) >> 16);
}

// ---------------------------------------------------------------------------
// embedding gather + dropout mask (fp32 variant for fallback)
// ---------------------------------------------------------------------------
__global__ void embed_kernel(const int* __restrict__ tok,
                             const float* __restrict__ table,
                             const float* __restrict__ mask,
                             float* __restrict__ emb) {
    int i = blockIdx.x * blockDim.x + threadIdx.x;
    const int n4 = NB * NE / 4;
    if (i >= n4) return;
    int b = i / (NE / 4);
    int c = i % (NE / 4);
    float4 t = ((const float4*)(table + (size_t)tok[b] * NE))[c];
    float4 m = ((const float4*)mask)[i];
    float4 o;
    o.x = t.x * m.x; o.y = t.y * m.y; o.z = t.z * m.z; o.w = t.w * m.w;
    ((float4*)emb)[i] = o;
}

// embedding gather + mask, split directly to bf16 hi/lo
__global__ void embed_split_kernel(const int* __restrict__ tok,
                                   const float* __restrict__ table,
                                   const float* __restrict__ mask,
                                   u16* __restrict__ ehi, u16* __restrict__ elo) {
    int i = blockIdx.x * blockDim.x + threadIdx.x;
    const int n4 = NB * NE / 4;
    if (i >= n4) return;
    int b = i / (NE / 4);
    int c = i % (NE / 4);
    float4 t = ((const float4*)(table + (size_t)tok[b] * NE))[c];
    float4 m = ((const float4*)mask)[i];
    float v[4] = {t.x * m.x, t.y * m.y, t.z * m.z, t.w * m.w};
    ushort4 h4, l4;
    split1(v[0], h4.x, l4.x); split1(v[1], h4.y, l4.y);
    split1(v[2], h4.z, l4.z); split1(v[3], h4.w, l4.w);
    ((ushort4*)ehi)[i] = h4;
    ((ushort4*)elo)[i] = l4;
}

// ---------------------------------------------------------------------------
// LIF recurrence. hsum = mask_lif * sum_t spike_t  (fp32 variant)
// ---------------------------------------------------------------------------
__global__ void lif_kernel(const float* __restrict__ delta1,
                           const float* __restrict__ hidden,
                           const float* __restrict__ mask_lif,
                           const float* __restrict__ thr_p,
                           const float* __restrict__ leak_p,
                           float* __restrict__ hsum) {
    int i = blockIdx.x * blockDim.x + threadIdx.x;
    if (i >= NB * NH) return;
    const float thr = thr_p[0];
    const float leak = leak_p[0];
    float d = delta1[i];
    float m = hidden[i];
    float cnt = 0.0f;
#pragma unroll
    for (int t = 0; t < TSTEPS; ++t) {
        float mem = leak * m + d;
        float s = ((mem / thr - 1.0f) > 0.0f) ? 1.0f : 0.0f;
        m = mem - thr * s;
        cnt += s;
    }
    hsum[i] = cnt * mask_lif[i];
}

// LIF recurrence, split output directly to bf16 hi/lo (4 elems/thread)
__global__ void lif_split_kernel(const float* __restrict__ delta1,
                                 const float* __restrict__ hidden,
                                 const float* __restrict__ mask_lif,
                                 const float* __restrict__ thr_p,
                                 const float* __restrict__ leak_p,
                                 u16* __restrict__ hhi, u16* __restrict__ hlo) {
    int i = blockIdx.x * blockDim.x + threadIdx.x;
    if (i >= NB * NH / 4) return;
    const float thr = thr_p[0];
    const float leak = leak_p[0];
    float4 d4 = ((const float4*)delta1)[i];
    float4 m4 = ((const float4*)hidden)[i];
    float4 k4 = ((const float4*)mask_lif)[i];
    float dd[4] = {d4.x, d4.y, d4.z, d4.w};
    float mm[4] = {m4.x, m4.y, m4.z, m4.w};
    float kk[4] = {k4.x, k4.y, k4.z, k4.w};
    ushort4 h4, l4;
    u16 hh[4], ll[4];
#pragma unroll
    for (int j = 0; j < 4; ++j) {
        float m = mm[j], cnt = 0.0f;
#pragma unroll
        for (int t = 0; t < TSTEPS; ++t) {
            float mem = leak * m + dd[j];
            float s = ((mem / thr - 1.0f) > 0.0f) ? 1.0f : 0.0f;
            m = mem - thr * s;
            cnt += s;
        }
        split1(cnt * kk[j], hh[j], ll[j]);
    }
    h4.x = hh[0]; h4.y = hh[1]; h4.z = hh[2]; h4.w = hh[3];
    l4.x = ll[0]; l4.y = ll[1]; l4.z = ll[2]; l4.w = ll[3];
    ((ushort4*)hhi)[i] = h4;
    ((ushort4*)hlo)[i] = l4;
}

// ---------------------------------------------------------------------------
// generic split kernel (for W1, W2, fc_W, outbuf)
// ---------------------------------------------------------------------------
__global__ void split4_kernel(const float* __restrict__ x,
                              u16* __restrict__ hi,
                              u16* __restrict__ lo, int n4) {
    int i0 = blockIdx.x * blockDim.x + threadIdx.x;
    int stride = gridDim.x * blockDim.x;
    for (int i = i0; i < n4; i += stride) {
        float4 v = ((const float4*)x)[i];
        float vv[4] = {v.x, v.y, v.z, v.w};
        ushort4 h4, l4;
        u16 hh[4], ll[4];
#pragma unroll
        for (int j = 0; j < 4; ++j) split1(vv[j], hh[j], ll[j]);
        h4.x = hh[0]; h4.y = hh[1]; h4.z = hh[2]; h4.w = hh[3];
        l4.x = ll[0]; l4.y = ll[1]; l4.z = ll[2]; l4.w = ll[3];
        ((ushort4*)hi)[i] = h4;
        ((ushort4*)lo)[i] = l4;
    }
}

// ---------------------------------------------------------------------------
// Split-bf16 MFMA GEMM body: C[m,n] = sum_k A[m,k]*B[n,k] + bias[n]*bias_scale
// 3-term: hi*hi + hi*lo + lo*hi.
// Fragment-linear LDS: tile stored as 1KB "units" of 16 rows x 32 k, element
// order = MFMA lane order (lane l: row 16u+(l&15), k (l>>4)*8). Staged via
// global_load_lds (linear dest) with pre-permuted per-lane GLOBAL address,
// so fragment ds_read_b128 is unit_base + l*16B -> conflict-free.
// Double-buffered, one __syncthreads per K-step (built-in vmcnt0 drain =
// minimal 2-phase pipeline: next-tile loads overlap current-tile MFMA).
// Requires M % TBM == 0, K % 32 == 0. N edge clamped/guarded.
// NOTE: plain __device__ body + concrete __global__ wrappers — template
// __global__ kernels fail to emit device stubs in this harness (round 3).
// ---------------------------------------------------------------------------
template<int TBM, int TBN, int NWAVE>
__device__ __forceinline__
void gemm_split_body(const u16* __restrict__ Ahi, const u16* __restrict__ Alo,
                     const u16* __restrict__ Bhi, const u16* __restrict__ Blo,
                     const float* __restrict__ bias, float bias_scale,
                     float* __restrict__ C, int M, int N, int K) {
    constexpr int AU = TBM / 16;            // A units per half (hi or lo)
    constexpr int BU = TBN / 16;
    constexpr int TOT = 2 * AU + 2 * BU;    // staged units per K-step
    constexpr int PER = TOT / NWAVE;        // units per wave
    constexpr int WCN = TBN / 64;           // wave-columns
    static_assert(TOT % NWAVE == 0, "chunk split");
    static_assert((TBM / 64) * WCN == NWAVE, "wave tiling");

    __shared__ u16 sA[2][2 * TBM * 32];     // [buf][hi | lo]
    __shared__ u16 sB[2][2 * TBN * 32];

    const int tid = threadIdx.x;
    const int w = tid >> 6;
    const int l = tid & 63;
    const int bm = blockIdx.y * TBM;
    const int bn = blockIdx.x * TBN;
    const int wr16 = (w / WCN) * 4;         // wave's A unit base
    const int wc16 = (w % WCN) * 4;         // wave's B unit base
    const int lrow = l & 15;                // staging: row within unit
    const int lcol = (l >> 4) * 8;          // staging: k within BK
    const int l8 = l * 8;                   // fragment read offset (ushorts)

    f32x4 acc[4][4];
#pragma unroll
    for (int m = 0; m < 4; ++m)
#pragma unroll
        for (int n = 0; n < 4; ++n)
#pragma unroll
            for (int q = 0; q < 4; ++q) acc[m][n][q] = 0.0f;

    const int NT = K / 32;

    auto stage = [&](int buf, int k0) {
#pragma unroll
        for (int i = 0; i < PER; ++i) {
            const int c = w + i * NWAVE;
            if (c < AU) {
                const int row = bm + c * 16 + lrow;
                __builtin_amdgcn_global_load_lds(Ahi + (size_t)row * K + k0 + lcol,
                                                 &sA[buf][c * 512], 16, 0, 0);
            } else if (c < 2 * AU) {
                const int u = c - AU;
                const int row = bm + u * 16 + lrow;
                __builtin_amdgcn_global_load_lds(Alo + (size_t)row * K + k0 + lcol,
                                                 &sA[buf][TBM * 32 + u * 512], 16, 0, 0);
            } else if (c < 2 * AU + BU) {
                const int u = c - 2 * AU;
                int row = bn + u * 16 + lrow; if (row >= N) row = N - 1;
                __builtin_amdgcn_global_load_lds(Bhi + (size_t)row * K + k0 + lcol,
                                                 &sB[buf][u * 512], 16, 0, 0);
            } else {
                const int u = c - 2 * AU - BU;
                int row = bn + u * 16 + lrow; if (row >= N) row = N - 1;
                __builtin_amdgcn_global_load_lds(Blo + (size_t)row * K + k0 + lcol,
                                                 &sB[buf][TBN * 32 + u * 512], 16, 0, 0);
            }
        }
    };

    stage(0, 0);
    __syncthreads();
    int cur = 0;
    for (int t = 0; t < NT; ++t) {
        if (t + 1 < NT) stage(cur ^ 1, (t + 1) * 32);

        bf16x8 ah[4], al[4], bh[4], bl[4];
#pragma unroll
        for (int m = 0; m < 4; ++m) {
            ah[m] = *(const bf16x8*)&sA[cur][(wr16 + m) * 512 + l8];
            al[m] = *(const bf16x8*)&sA[cur][TBM * 32 + (wr16 + m) * 512 + l8];
        }
#pragma unroll
        for (int n = 0; n < 4; ++n) {
            bh[n] = *(const bf16x8*)&sB[cur][(wc16 + n) * 512 + l8];
            bl[n] = *(const bf16x8*)&sB[cur][TBN * 32 + (wc16 + n) * 512 + l8];
        }

#pragma unroll
        for (int m = 0; m < 4; ++m)
#pragma unroll
            for (int n = 0; n < 4; ++n) {
                acc[m][n] = __builtin_amdgcn_mfma_f32_16x16x32_bf16(ah[m], bh[n], acc[m][n], 0, 0, 0);
                acc[m][n] = __builtin_amdgcn_mfma_f32_16x16x32_bf16(ah[m], bl[n], acc[m][n], 0, 0, 0);
                acc[m][n] = __builtin_amdgcn_mfma_f32_16x16x32_bf16(al[m], bh[n], acc[m][n], 0, 0, 0);
            }
        __syncthreads();
        cur ^= 1;
    }

    // epilogue: C/D layout col = l&15, row = (l>>4)*4 + reg
    const int lq = (l >> 4) * 4;
    const int wrow = bm + (w / WCN) * 64;
    const int wcol = bn + (w % WCN) * 64;
#pragma unroll
    for (int n = 0; n < 4; ++n) {
        const int gcol = wcol + n * 16 + (l & 15);
        if (gcol >= N) continue;
        const float bb = bias[gcol] * bias_scale;
#pragma unroll
        for (int m = 0; m < 4; ++m) {
            const int grow = wrow + m * 16 + lq;
#pragma unroll
            for (int q = 0; q < 4; ++q)
                C[(size_t)(grow + q) * N + gcol] = acc[m][n][q] + bb;
        }
    }
}

// concrete wrappers (no template __global__ — see round-3 link failure)
__global__ __launch_bounds__(256)
void gemm_split_128(const u16* __restrict__ Ahi, const u16* __restrict__ Alo,
                    const u16* __restrict__ Bhi, const u16* __restrict__ Blo,
                    const float* __restrict__ bias, float bias_scale,
                    float* __restrict__ C, int M, int N, int K) {
    gemm_split_body<128, 128, 4>(Ahi, Alo, Bhi, Blo, bias, bias_scale, C, M, N, K);
}

__global__ __launch_bounds__(512)
void gemm_split_256(const u16* __restrict__ Ahi, const u16* __restrict__ Alo,
                    const u16* __restrict__ Bhi, const u16* __restrict__ Blo,
                    const float* __restrict__ bias, float bias_scale,
                    float* __restrict__ C, int M, int N, int K) {
    gemm_split_body<256, 128, 8>(Ahi, Alo, Bhi, Blo, bias, bias_scale, C, M, N, K);
}

// ---------------------------------------------------------------------------
// fp32 NT GEMM (fallback): C = A*B^T + bias*bias_scale
// ---------------------------------------------------------------------------
#define BM 128
#define BN 128
#define BK 16

__global__ __launch_bounds__(256)
void gemm_nt(const float* __restrict__ A, const float* __restrict__ Bm,
             const float* __restrict__ bias, float bias_scale,
             float* __restrict__ C, int M, int N, int K) {
    __shared__ float As[BK][BM + 4];
    __shared__ float Bs[BK][BN + 4];

    const int tid = threadIdx.x;
    const int bm = blockIdx.y * BM;
    const int bn = blockIdx.x * BN;
    const int tx = tid & 15;
    const int ty = tid >> 4;
    const int tm = ty * 8;
    const int tn0 = tx * 4;
    const int tn1 = 64 + tx * 4;

    float acc[8][8];
#pragma unroll
    for (int i = 0; i < 8; ++i)
#pragma unroll
        for (int j = 0; j < 8; ++j) acc[i][j] = 0.0f;

    constexpr int LDA4 = BK / 4;

    for (int k0 = 0; k0 < K; k0 += BK) {
#pragma unroll
        for (int idx = tid; idx < BM * LDA4; idx += 256) {
            int m = idx / LDA4, c = idx % LDA4;
            float4 v = *(const float4*)(A + (size_t)(bm + m) * K + k0 + c * 4);
            As[c * 4 + 0][m] = v.x;
            As[c * 4 + 1][m] = v.y;
            As[c * 4 + 2][m] = v.z;
            As[c * 4 + 3][m] = v.w;
        }
#pragma unroll
        for (int idx = tid; idx < BN * LDA4; idx += 256) {
            int n = idx / LDA4, c = idx % LDA4;
            float4 v = make_float4(0.f, 0.f, 0.f, 0.f);
            int gn = bn + n;
            if (gn < N) v = *(const float4*)(Bm + (size_t)gn * K + k0 + c * 4);
            Bs[c * 4 + 0][n] = v.x;
            Bs[c * 4 + 1][n] = v.y;
            Bs[c * 4 + 2][n] = v.z;
            Bs[c * 4 + 3][n] = v.w;
        }
        __syncthreads();

#pragma unroll
        for (int k = 0; k < BK; ++k) {
            float4 a0 = *(const float4*)&As[k][tm];
            float4 a1 = *(const float4*)&As[k][tm + 4];
            float4 b0 = *(const float4*)&Bs[k][tn0];
            float4 b1 = *(const float4*)&Bs[k][tn1];
            float a[8] = {a0.x, a0.y, a0.z, a0.w, a1.x, a1.y, a1.z, a1.w};
            float bb[8] = {b0.x, b0.y, b0.z, b0.w, b1.x, b1.y, b1.z, b1.w};
#pragma unroll
            for (int i = 0; i < 8; ++i)
#pragma unroll
                for (int j = 0; j < 8; ++j)
                    acc[i][j] = fmaf(a[i], bb[j], acc[i][j]);
        }
        __syncthreads();
    }

    if (bn + BN <= N) {
        float4 c0 = *(const float4*)&bias[bn + tn0];
        float4 c1 = *(const float4*)&bias[bn + tn1];
        c0.x *= bias_scale; c0.y *= bias_scale; c0.z *= bias_scale; c0.w *= bias_scale;
        c1.x *= bias_scale; c1.y *= bias_scale; c1.z *= bias_scale; c1.w *= bias_scale;
#pragma unroll
        for (int i = 0; i < 8; ++i) {
            size_t row = (size_t)(bm + tm + i) * N;
            float4 v0, v1;
            v0.x = acc[i][0] + c0.x; v0.y = acc[i][1] + c0.y;
            v0.z = acc[i][2] + c0.z; v0.w = acc[i][3] + c0.w;
            v1.x = acc[i][4] + c1.x; v1.y = acc[i][5] + c1.y;
            v1.z = acc[i][6] + c1.z; v1.w = acc[i][7] + c1.w;
            *(float4*)(C + row + bn + tn0) = v0;
            *(float4*)(C + row + bn + tn1) = v1;
        }
    } else {
#pragma unroll
        for (int i = 0; i < 8; ++i) {
            size_t row = (size_t)(bm + tm + i) * N;
#pragma unroll
            for (int j = 0; j < 8; ++j) {
                int gn = bn + ((j < 4) ? (tn0 + j) : (tn1 + j - 4));
                if (gn < N)
                    C[row + gn] = acc[i][j] + bias[gn] * bias_scale;
            }
        }
    }
}

// ---------------------------------------------------------------------------
extern "C" void kernel_launch(void* const* d_in, const int* in_sizes, int n_in,
                              void* d_out, int out_size, void* d_ws, size_t ws_size,
                              hipStream_t stream) {
    const int*   tok      = (const int*)  d_in[0];
    const float* hidden   = (const float*)d_in[1];
    const float* table    = (const float*)d_in[2];
    const float* W1       = (const float*)d_in[3];
    const float* b1       = (const float*)d_in[4];
    const float* W2       = (const float*)d_in[5];
    const float* b2       = (const float*)d_in[6];
    const float* fc_W     = (const float*)d_in[7];
    const float* fc_b     = (const float*)d_in[8];
    const float* thr      = (const float*)d_in[9];
    const float* leak     = (const float*)d_in[10];
    const float* mask_emb = (const float*)d_in[11];
    const float* mask_lif = (const float*)d_in[12];

    float* linear = (float*)d_out;                   // [B,V]
    float* outbuf = (float*)d_out + (size_t)NB * NV; // [B,H]

    const size_t SZ_D1 = (size_t)NB * NH * 4;   // delta1 fp32
    const size_t SZ_E  = (size_t)NB * NE * 2;   // emb bf16 half
    const size_t SZ_W1 = (size_t)NH * NE * 2;
    const size_t SZ_H  = (size_t)NB * NH * 2;
    const size_t SZ_W2 = (size_t)NH * NH * 2;
    const size_t SZ_O  = (size_t)NB * NH * 2;
    const size_t SZ_W  = (size_t)NV * NH * 2;   // fc_W bf16 half (~103 MB)

    const size_t need_full = SZ_D1 + 2*SZ_E + 2*SZ_W1 + 2*SZ_H + 2*SZ_W2 + 2*SZ_O + 2*SZ_W;
    const size_t need_part = (size_t)NB*NE*4 + SZ_D1 + (size_t)NB*NH*4 + 2*SZ_O + 2*SZ_W;

    char* p = (char*)d_ws;

    if (ws_size >= need_full) {
        // ----- full MFMA path -----
        float* delta1 = (float*)p;  p += SZ_D1;
        u16* e_hi = (u16*)p; p += SZ_E;   u16* e_lo = (u16*)p; p += SZ_E;
        u16* w1h  = (u16*)p; p += SZ_W1;  u16* w1l  = (u16*)p; p += SZ_W1;
        u16* h_hi = (u16*)p; p += SZ_H;   u16* h_lo = (u16*)p; p += SZ_H;
        u16* w2h  = (u16*)p; p += SZ_W2;  u16* w2l  = (u16*)p; p += SZ_W2;
        u16* o_hi = (u16*)p; p += SZ_O;   u16* o_lo = (u16*)p; p += SZ_O;
        u16* w_hi = (u16*)p; p += SZ_W;   u16* w_lo = (u16*)p; p += SZ_W;

        // big weight split first (largest kernel; single stream so order is FIFO)
        split4_kernel<<<2048, 256, 0, stream>>>(fc_W, w_hi, w_lo, NV * NH / 4);
        {
            int n4 = NB * NE / 4;
            embed_split_kernel<<<(n4 + 255) / 256, 256, 0, stream>>>(tok, table, mask_emb, e_hi, e_lo);
        }
        split4_kernel<<<512, 256, 0, stream>>>(W1, w1h, w1l, NH * NE / 4);
        split4_kernel<<<1024, 256, 0, stream>>>(W2, w2h, w2l, NH * NH / 4);
        // delta1 = emb @ W1^T + b1
        {
            dim3 grid(NH / 128, NB / 128);
            gemm_split_128<<<grid, 256, 0, stream>>>(e_hi, e_lo, w1h, w1l,
                                                     b1, 1.0f, delta1, NB, NH, NE);
        }
        // LIF -> hsum (split)
        {
            int n = NB * NH / 4;
            lif_split_kernel<<<(n + 255) / 256, 256, 0, stream>>>(delta1, hidden, mask_lif,
                                                                  thr, leak, h_hi, h_lo);
        }
        // out = hsum @ W2^T + 10*b2
        {
            dim3 grid(NH / 128, NB / 128);
            gemm_split_128<<<grid, 256, 0, stream>>>(h_hi, h_lo, w2h, w2l,
                                                     b2, (float)TSTEPS, outbuf, NB, NH, NH);
        }
        // split out
        split4_kernel<<<1024, 256, 0, stream>>>(outbuf, o_hi, o_lo, NB * NH / 4);
        // linear = out @ fc_W^T + fc_b
        {
            dim3 grid((NV + 127) / 128, NB / 256);
            gemm_split_256<<<grid, 512, 0, stream>>>(o_hi, o_lo, w_hi, w_lo,
                                                     fc_b, 1.0f, linear, NB, NV, NH);
        }
    } else if (ws_size >= need_part) {
        // ----- partial: fp32 small path + MFMA big GEMM (round-2 footprint) -----
        float* emb    = (float*)p;  p += (size_t)NB * NE * 4;
        float* delta1 = (float*)p;  p += SZ_D1;
        float* hsum   = (float*)p;  p += (size_t)NB * NH * 4;
        u16* o_hi = (u16*)p; p += SZ_O;   u16* o_lo = (u16*)p; p += SZ_O;
        u16* w_hi = (u16*)p; p += SZ_W;   u16* w_lo = (u16*)p; p += SZ_W;

        int n4 = NB * NE / 4;
        embed_kernel<<<(n4 + 255) / 256, 256, 0, stream>>>(tok, table, mask_emb, emb);
        {
            dim3 grid(NH / BN, NB / BM);
            gemm_nt<<<grid, 256, 0, stream>>>(emb, W1, b1, 1.0f, delta1, NB, NH, NE);
        }
        {
            int n = NB * NH;
            lif_kernel<<<(n + 255) / 256, 256, 0, stream>>>(delta1, hidden, mask_lif,
                                                            thr, leak, hsum);
        }
        {
            dim3 grid(NH / BN, NB / BM);
            gemm_nt<<<grid, 256, 0, stream>>>(hsum, W2, b2, (float)TSTEPS, outbuf, NB, NH, NH);
        }
        split4_kernel<<<2048, 256, 0, stream>>>(fc_W, w_hi, w_lo, NV * NH / 4);
        split4_kernel<<<1024, 256, 0, stream>>>(outbuf, o_hi, o_lo, NB * NH / 4);
        {
            dim3 grid((NV + 127) / 128, NB / 256);
            gemm_split_256<<<grid, 512, 0, stream>>>(o_hi, o_lo, w_hi, w_lo,
                                                     fc_b, 1.0f, linear, NB, NV, NH);
        }
    } else {
        // ----- pure fp32 fallback -----
        float* emb    = (float*)p;  p += (size_t)NB * NE * 4;
        float* delta1 = (float*)p;  p += SZ_D1;
        float* hsum   = (float*)p;

        int n4 = NB * NE / 4;
        embed_kernel<<<(n4 + 255) / 256, 256, 0, stream>>>(tok, table, mask_emb, emb);
        {
            dim3 grid(NH / BN, NB / BM);
            gemm_nt<<<grid, 256, 0, stream>>>(emb, W1, b1, 1.0f, delta1, NB, NH, NE);
        }
        {
            int n = NB * NH;
            lif_kernel<<<(n + 255) / 256, 256, 0, stream>>>(delta1, hidden, mask_lif,
                                                            thr, leak, hsum);
        }
        {
            dim3 grid(NH / BN, NB / BM);
            gemm_nt<<<grid, 256, 0, stream>>>(hsum, W2, b2, (float)TSTEPS, outbuf, NB, NH, NH);
        }
        {
            dim3 grid((NV + BN - 1) / BN, NB / BM);
            gemm_nt<<<grid, 256, 0, stream>>>(outbuf, fc_W, fc_b, 1.0f, linear, NB, NV, NH);
        }
    }
}

// Round 5
// 417.664 us; speedup vs baseline: 3.0570x; 1.6828x over previous
//
#include <hip/hip_runtime.h>

#define NV 50257
#define NE 512
#define NH 1024
#define NB 1024
#define TSTEPS 10

typedef __bf16 bf16x8 __attribute__((ext_vector_type(8)));
typedef float  f32x4  __attribute__((ext_vector_type(4)));
typedef unsigned short u16;
typedef unsigned short u16x8 __attribute__((ext_vector_type(8)));

// fp32 -> bf16 round-to-nearest-even
__device__ __forceinline__ u16 f2bf(float v) {
    unsigned u = __float_as_uint(v);
    unsigned r = u + 0x7fffu + ((u >> 16) & 1u);
    return (u16)(r >> 16);
}

// ---------------------------------------------------------------------------
// embedding gather + dropout mask -> bf16
// ---------------------------------------------------------------------------
__global__ void embed_bf16_kernel(const int* __restrict__ tok,
                                  const float* __restrict__ table,
                                  const float* __restrict__ mask,
                                  u16* __restrict__ ebf) {
    int i = blockIdx.x * blockDim.x + threadIdx.x;   // float4 index
    const int n4 = NB * NE / 4;
    if (i >= n4) return;
    int b = i / (NE / 4);
    int c = i % (NE / 4);
    float4 t = ((const float4*)(table + (size_t)tok[b] * NE))[c];
    float4 m = ((const float4*)mask)[i];
    ushort4 o;
    o.x = f2bf(t.x * m.x); o.y = f2bf(t.y * m.y);
    o.z = f2bf(t.z * m.z); o.w = f2bf(t.w * m.w);
    ((ushort4*)ebf)[i] = o;
}

// ---------------------------------------------------------------------------
// LIF recurrence -> hsum = mask_lif * sum_t spike_t, output bf16
// ---------------------------------------------------------------------------
__global__ void lif_bf16_kernel(const float* __restrict__ delta1,
                                const float* __restrict__ hidden,
                                const float* __restrict__ mask_lif,
                                const float* __restrict__ thr_p,
                                const float* __restrict__ leak_p,
                                u16* __restrict__ hbf) {
    int i = blockIdx.x * blockDim.x + threadIdx.x;
    if (i >= NB * NH / 4) return;
    const float thr = thr_p[0];
    const float leak = leak_p[0];
    float4 d4 = ((const float4*)delta1)[i];
    float4 m4 = ((const float4*)hidden)[i];
    float4 k4 = ((const float4*)mask_lif)[i];
    float dd[4] = {d4.x, d4.y, d4.z, d4.w};
    float mm[4] = {m4.x, m4.y, m4.z, m4.w};
    float kk[4] = {k4.x, k4.y, k4.z, k4.w};
    ushort4 o;
    u16 oo[4];
#pragma unroll
    for (int j = 0; j < 4; ++j) {
        float m = mm[j], cnt = 0.0f;
#pragma unroll
        for (int t = 0; t < TSTEPS; ++t) {
            float mem = leak * m + dd[j];
            float s = ((mem / thr - 1.0f) > 0.0f) ? 1.0f : 0.0f;
            m = mem - thr * s;
            cnt += s;
        }
        oo[j] = f2bf(cnt * kk[j]);
    }
    o.x = oo[0]; o.y = oo[1]; o.z = oo[2]; o.w = oo[3];
    ((ushort4*)hbf)[i] = o;
}

// ---------------------------------------------------------------------------
// bf16-A x fp32-B MFMA GEMM: C[m,n] = sum_k A[m,k]*B[n,k] + bias[n]*scale
// A: bf16 [M,K] row-major (gload_lds, fragment-linear LDS units of
//    16 rows x 32 k, lane l -> row l&15, k (l>>4)*8 -> conflict-free
//    ds_read_b128 at unit_base + l*16B).
// B: fp32 [N,K] row-major, reg-staged: issue 2xfloat4 loads early,
//    cvt->ds_write_b128 AFTER the MFMA cluster (T14 write-late) so HBM
//    latency hides under compute. Same fragment-linear layout.
// Double-buffered (48 KB for 256x128), one __syncthreads per K-step
// (built-in vmcnt/lgkm drain completes next tile). 2-3 blocks/CU.
// Optional bf16 mirror output Cb (for feeding the next GEMM).
// Requires M % TBM == 0, K % 32 == 0. N edge clamped/guarded.
// NOTE: concrete __global__ wrappers (template __global__ fails to link
// in this harness — round 3).
// ---------------------------------------------------------------------------
template<int TBM, int TBN, int NWAVE>
__device__ __forceinline__
void gemm_ab_body(const u16* __restrict__ Abf, const float* __restrict__ Bf,
                  const float* __restrict__ bias, float bias_scale,
                  float* __restrict__ C, u16* __restrict__ Cb,
                  int M, int N, int K) {
    constexpr int AU = TBM / 16;            // A units (1KB each)
    constexpr int BU = TBN / 16;            // B units
    constexpr int APW = AU / NWAVE;         // A units per wave (gload_lds)
    constexpr int BPT = BU / NWAVE > 0 ? BU / NWAVE : 1;  // B units per thread-group
    constexpr int WCN = TBN / 64;           // wave-columns
    static_assert(AU % NWAVE == 0, "A unit split");
    static_assert(BU % NWAVE == 0 || NWAVE % BU == 0, "B unit split");
    static_assert((TBM / 64) * WCN == NWAVE, "wave tiling");

    __shared__ u16 sA[2][TBM * 32];
    __shared__ u16 sB[2][TBN * 32];

    const int tid = threadIdx.x;
    const int w = tid >> 6;
    const int l = tid & 63;
    const int bm = blockIdx.y * TBM;
    const int bn = blockIdx.x * TBN;
    const int wr16 = (w / WCN) * 4;         // wave's A unit base
    const int wc16 = (w % WCN) * 4;         // wave's B unit base
    const int lrow = l & 15;                // row within unit
    const int lk8 = (l >> 4) * 8;           // k offset within BK=32
    const int l8 = l * 8;                   // fragment read offset (u16)

    f32x4 acc[4][4];
#pragma unroll
    for (int m = 0; m < 4; ++m)
#pragma unroll
        for (int n = 0; n < 4; ++n)
#pragma unroll
            for (int q = 0; q < 4; ++q) acc[m][n][q] = 0.0f;

    const int NT = K / 32;

    auto loadB = [&](int k0, float4* b0, float4* b1) {
#pragma unroll
        for (int i = 0; i < BPT; ++i) {
            const int u = w + i * NWAVE;
            if (u >= BU) break;
            int row = bn + u * 16 + lrow; if (row >= N) row = N - 1;
            const float* src = Bf + (size_t)row * K + k0 + lk8;
            b0[i] = *(const float4*)src;
            b1[i] = *(const float4*)(src + 4);
        }
    };
    auto issueA = [&](int buf, int k0) {
#pragma unroll
        for (int i = 0; i < APW; ++i) {
            const int u = w + i * NWAVE;
            const int row = bm + u * 16 + lrow;
            __builtin_amdgcn_global_load_lds(Abf + (size_t)row * K + k0 + lk8,
                                             &sA[buf][u * 512], 16, 0, 0);
        }
    };
    auto writeB = [&](int buf, const float4* b0, const float4* b1) {
#pragma unroll
        for (int i = 0; i < BPT; ++i) {
            const int u = w + i * NWAVE;
            if (u >= BU) break;
            u16x8 pk;
            pk[0] = f2bf(b0[i].x); pk[1] = f2bf(b0[i].y);
            pk[2] = f2bf(b0[i].z); pk[3] = f2bf(b0[i].w);
            pk[4] = f2bf(b1[i].x); pk[5] = f2bf(b1[i].y);
            pk[6] = f2bf(b1[i].z); pk[7] = f2bf(b1[i].w);
            *(u16x8*)&sB[buf][u * 512 + l8] = pk;
        }
    };

    // prologue: stage tile 0
    {
        float4 b0[BPT], b1[BPT];
        loadB(0, b0, b1);
        issueA(0, 0);
        writeB(0, b0, b1);
    }
    __syncthreads();

    int cur = 0;
    for (int t = 0; t < NT; ++t) {
        const bool np = (t + 1 < NT);
        float4 b0[BPT], b1[BPT];
        if (np) {
            loadB((t + 1) * 32, b0, b1);        // issue early (latency hides)
            issueA(cur ^ 1, (t + 1) * 32);
        }

        bf16x8 ah[4], bh[4];
#pragma unroll
        for (int m = 0; m < 4; ++m)
            ah[m] = *(const bf16x8*)&sA[cur][(wr16 + m) * 512 + l8];
#pragma unroll
        for (int n = 0; n < 4; ++n)
            bh[n] = *(const bf16x8*)&sB[cur][(wc16 + n) * 512 + l8];

#pragma unroll
        for (int m = 0; m < 4; ++m)
#pragma unroll
            for (int n = 0; n < 4; ++n)
                acc[m][n] = __builtin_amdgcn_mfma_f32_16x16x32_bf16(ah[m], bh[n], acc[m][n], 0, 0, 0);

        if (np) writeB(cur ^ 1, b0, b1);        // write-late (T14)
        __syncthreads();
        cur ^= 1;
    }

    // epilogue: C/D layout col = l&15, row = (l>>4)*4 + reg
    const int lq = (l >> 4) * 4;
    const int wrow = bm + (w / WCN) * 64;
    const int wcol = bn + (w % WCN) * 64;
#pragma unroll
    for (int n = 0; n < 4; ++n) {
        const int gcol = wcol + n * 16 + (l & 15);
        if (gcol >= N) continue;
        const float bb = bias[gcol] * bias_scale;
#pragma unroll
        for (int m = 0; m < 4; ++m) {
            const int grow = wrow + m * 16 + lq;
#pragma unroll
            for (int q = 0; q < 4; ++q) {
                float v = acc[m][n][q] + bb;
                C[(size_t)(grow + q) * N + gcol] = v;
                if (Cb) Cb[(size_t)(grow + q) * N + gcol] = f2bf(v);
            }
        }
    }
}

__global__ __launch_bounds__(256, 4)
void gemm_ab_128(const u16* __restrict__ Abf, const float* __restrict__ Bf,
                 const float* __restrict__ bias, float bias_scale,
                 float* __restrict__ C, u16* __restrict__ Cb, int M, int N, int K) {
    gemm_ab_body<128, 128, 4>(Abf, Bf, bias, bias_scale, C, Cb, M, N, K);
}

__global__ __launch_bounds__(512, 4)
void gemm_ab_256(const u16* __restrict__ Abf, const float* __restrict__ Bf,
                 const float* __restrict__ bias, float bias_scale,
                 float* __restrict__ C, u16* __restrict__ Cb, int M, int N, int K) {
    gemm_ab_body<256, 128, 8>(Abf, Bf, bias, bias_scale, C, Cb, M, N, K);
}

// ---------------------------------------------------------------------------
// fp32 fallback kernels (tiny-workspace safety net)
// ---------------------------------------------------------------------------
__global__ void embed_kernel(const int* __restrict__ tok,
                             const float* __restrict__ table,
                             const float* __restrict__ mask,
                             float* __restrict__ emb) {
    int i = blockIdx.x * blockDim.x + threadIdx.x;
    const int n4 = NB * NE / 4;
    if (i >= n4) return;
    int b = i / (NE / 4);
    int c = i % (NE / 4);
    float4 t = ((const float4*)(table + (size_t)tok[b] * NE))[c];
    float4 m = ((const float4*)mask)[i];
    float4 o;
    o.x = t.x * m.x; o.y = t.y * m.y; o.z = t.z * m.z; o.w = t.w * m.w;
    ((float4*)emb)[i] = o;
}

__global__ void lif_kernel(const float* __restrict__ delta1,
                           const float* __restrict__ hidden,
                           const float* __restrict__ mask_lif,
                           const float* __restrict__ thr_p,
                           const float* __restrict__ leak_p,
                           float* __restrict__ hsum) {
    int i = blockIdx.x * blockDim.x + threadIdx.x;
    if (i >= NB * NH) return;
    const float thr = thr_p[0];
    const float leak = leak_p[0];
    float d = delta1[i];
    float m = hidden[i];
    float cnt = 0.0f;
#pragma unroll
    for (int t = 0; t < TSTEPS; ++t) {
        float mem = leak * m + d;
        float s = ((mem / thr - 1.0f) > 0.0f) ? 1.0f : 0.0f;
        m = mem - thr * s;
        cnt += s;
    }
    hsum[i] = cnt * mask_lif[i];
}

#define BM 128
#define BN 128
#define BK 16

__global__ __launch_bounds__(256)
void gemm_nt(const float* __restrict__ A, const float* __restrict__ Bm,
             const float* __restrict__ bias, float bias_scale,
             float* __restrict__ C, int M, int N, int K) {
    __shared__ float As[BK][BM + 4];
    __shared__ float Bs[BK][BN + 4];

    const int tid = threadIdx.x;
    const int bm = blockIdx.y * BM;
    const int bn = blockIdx.x * BN;
    const int tx = tid & 15;
    const int ty = tid >> 4;
    const int tm = ty * 8;
    const int tn0 = tx * 4;
    const int tn1 = 64 + tx * 4;

    float acc[8][8];
#pragma unroll
    for (int i = 0; i < 8; ++i)
#pragma unroll
        for (int j = 0; j < 8; ++j) acc[i][j] = 0.0f;

    constexpr int LDA4 = BK / 4;

    for (int k0 = 0; k0 < K; k0 += BK) {
#pragma unroll
        for (int idx = tid; idx < BM * LDA4; idx += 256) {
            int m = idx / LDA4, c = idx % LDA4;
            float4 v = *(const float4*)(A + (size_t)(bm + m) * K + k0 + c * 4);
            As[c * 4 + 0][m] = v.x;
            As[c * 4 + 1][m] = v.y;
            As[c * 4 + 2][m] = v.z;
            As[c * 4 + 3][m] = v.w;
        }
#pragma unroll
        for (int idx = tid; idx < BN * LDA4; idx += 256) {
            int n = idx / LDA4, c = idx % LDA4;
            float4 v = make_float4(0.f, 0.f, 0.f, 0.f);
            int gn = bn + n;
            if (gn < N) v = *(const float4*)(Bm + (size_t)gn * K + k0 + c * 4);
            Bs[c * 4 + 0][n] = v.x;
            Bs[c * 4 + 1][n] = v.y;
            Bs[c * 4 + 2][n] = v.z;
            Bs[c * 4 + 3][n] = v.w;
        }
        __syncthreads();

#pragma unroll
        for (int k = 0; k < BK; ++k) {
            float4 a0 = *(const float4*)&As[k][tm];
            float4 a1 = *(const float4*)&As[k][tm + 4];
            float4 b0 = *(const float4*)&Bs[k][tn0];
            float4 b1 = *(const float4*)&Bs[k][tn1];
            float a[8] = {a0.x, a0.y, a0.z, a0.w, a1.x, a1.y, a1.z, a1.w};
            float bb[8] = {b0.x, b0.y, b0.z, b0.w, b1.x, b1.y, b1.z, b1.w};
#pragma unroll
            for (int i = 0; i < 8; ++i)
#pragma unroll
                for (int j = 0; j < 8; ++j)
                    acc[i][j] = fmaf(a[i], bb[j], acc[i][j]);
        }
        __syncthreads();
    }

    if (bn + BN <= N) {
#pragma unroll
        for (int i = 0; i < 8; ++i) {
            size_t row = (size_t)(bm + tm + i) * N;
#pragma unroll
            for (int j = 0; j < 8; ++j) {
                int gn = bn + ((j < 4) ? (tn0 + j) : (tn1 + j - 4));
                C[row + gn] = acc[i][j] + bias[gn] * bias_scale;
            }
        }
    } else {
#pragma unroll
        for (int i = 0; i < 8; ++i) {
            size_t row = (size_t)(bm + tm + i) * N;
#pragma unroll
            for (int j = 0; j < 8; ++j) {
                int gn = bn + ((j < 4) ? (tn0 + j) : (tn1 + j - 4));
                if (gn < N)
                    C[row + gn] = acc[i][j] + bias[gn] * bias_scale;
            }
        }
    }
}

// ---------------------------------------------------------------------------
extern "C" void kernel_launch(void* const* d_in, const int* in_sizes, int n_in,
                              void* d_out, int out_size, void* d_ws, size_t ws_size,
                              hipStream_t stream) {
    const int*   tok      = (const int*)  d_in[0];
    const float* hidden   = (const float*)d_in[1];
    const float* table    = (const float*)d_in[2];
    const float* W1       = (const float*)d_in[3];
    const float* b1       = (const float*)d_in[4];
    const float* W2       = (const float*)d_in[5];
    const float* b2       = (const float*)d_in[6];
    const float* fc_W     = (const float*)d_in[7];
    const float* fc_b     = (const float*)d_in[8];
    const float* thr      = (const float*)d_in[9];
    const float* leak     = (const float*)d_in[10];
    const float* mask_emb = (const float*)d_in[11];
    const float* mask_lif = (const float*)d_in[12];

    float* linear = (float*)d_out;                   // [B,V]
    float* outbuf = (float*)d_out + (size_t)NB * NV; // [B,H]

    const size_t SZ_EB = (size_t)NB * NE * 2;   // ebf
    const size_t SZ_D1 = (size_t)NB * NH * 4;   // delta1 fp32
    const size_t SZ_HB = (size_t)NB * NH * 2;   // hbf
    const size_t SZ_OB = (size_t)NB * NH * 2;   // obf
    const size_t need_bf = SZ_EB + SZ_D1 + SZ_HB + SZ_OB;   // ~9.5 MB

    char* p = (char*)d_ws;

    if (ws_size >= need_bf) {
        u16*   ebf    = (u16*)p;   p += SZ_EB;
        float* delta1 = (float*)p; p += SZ_D1;
        u16*   hbf    = (u16*)p;   p += SZ_HB;
        u16*   obf    = (u16*)p;   p += SZ_OB;

        // 0: embedding gather + mask -> bf16
        {
            int n4 = NB * NE / 4;
            embed_bf16_kernel<<<(n4 + 255) / 256, 256, 0, stream>>>(tok, table, mask_emb, ebf);
        }
        // 1: delta1 = ebf @ W1^T + b1   (M=B, N=H, K=E) ; W1 fp32 reg-staged
        {
            dim3 grid(NH / 128, NB / 128);
            gemm_ab_128<<<grid, 256, 0, stream>>>(ebf, W1, b1, 1.0f,
                                                  delta1, (u16*)nullptr, NB, NH, NE);
        }
        // 2: LIF -> hbf (bf16)
        {
            int n = NB * NH / 4;
            lif_bf16_kernel<<<(n + 255) / 256, 256, 0, stream>>>(delta1, hidden, mask_lif,
                                                                 thr, leak, hbf);
        }
        // 3: out = hbf @ W2^T + 10*b2 -> outbuf (fp32, second output) + obf (bf16)
        {
            dim3 grid(NH / 128, NB / 128);
            gemm_ab_128<<<grid, 256, 0, stream>>>(hbf, W2, b2, (float)TSTEPS,
                                                  outbuf, obf, NB, NH, NH);
        }
        // 4: linear = obf @ fc_W^T + fc_b  (M=B, N=V, K=H) ; fc_W fp32 reg-staged
        {
            dim3 grid((NV + 127) / 128, NB / 256);
            gemm_ab_256<<<grid, 512, 0, stream>>>(obf, fc_W, fc_b, 1.0f,
                                                  linear, (u16*)nullptr, NB, NV, NH);
        }
    } else {
        // ----- pure fp32 fallback -----
        float* emb    = (float*)p;  p += (size_t)NB * NE * 4;
        float* delta1 = (float*)p;  p += SZ_D1;
        float* hsum   = (float*)p;

        int n4 = NB * NE / 4;
        embed_kernel<<<(n4 + 255) / 256, 256, 0, stream>>>(tok, table, mask_emb, emb);
        {
            dim3 grid(NH / BN, NB / BM);
            gemm_nt<<<grid, 256, 0, stream>>>(emb, W1, b1, 1.0f, delta1, NB, NH, NE);
        }
        {
            int n = NB * NH;
            lif_kernel<<<(n + 255) / 256, 256, 0, stream>>>(delta1, hidden, mask_lif,
                                                            thr, leak, hsum);
        }
        {
            dim3 grid(NH / BN, NB / BM);
            gemm_nt<<<grid, 256, 0, stream>>>(hsum, W2, b2, (float)TSTEPS, outbuf, NB, NH, NH);
        }
        {
            dim3 grid((NV + BN - 1) / BN, NB / BM);
            gemm_nt<<<grid, 256, 0, stream>>>(outbuf, fc_W, fc_b, 1.0f, linear, NB, NV, NH);
        }
    }
}

// Round 6
// 406.129 us; speedup vs baseline: 3.1438x; 1.0284x over previous
//
#include <hip/hip_runtime.h>

#define NV 50257
#define NE 512
#define NH 1024
#define NB 1024
#define TSTEPS 10

typedef __bf16 bf16x8 __attribute__((ext_vector_type(8)));
typedef float  f32x4  __attribute__((ext_vector_type(4)));
typedef unsigned short u16;

// fp32 -> bf16 round-to-nearest-even
__device__ __forceinline__ u16 f2bf(float v) {
    unsigned u = __float_as_uint(v);
    unsigned r = u + 0x7fffu + ((u >> 16) & 1u);
    return (u16)(r >> 16);
}

// ---------------------------------------------------------------------------
// streaming fp32 -> bf16 convert (fc_W, W1, W2)
// ---------------------------------------------------------------------------
__global__ void cvt_bf16_kernel(const float* __restrict__ x,
                                u16* __restrict__ y, int n4) {
    int i0 = blockIdx.x * blockDim.x + threadIdx.x;
    int stride = gridDim.x * blockDim.x;
    for (int i = i0; i < n4; i += stride) {
        float4 v = ((const float4*)x)[i];
        ushort4 o;
        o.x = f2bf(v.x); o.y = f2bf(v.y); o.z = f2bf(v.z); o.w = f2bf(v.w);
        ((ushort4*)y)[i] = o;
    }
}

// ---------------------------------------------------------------------------
// embedding gather + dropout mask -> bf16
// ---------------------------------------------------------------------------
__global__ void embed_bf16_kernel(const int* __restrict__ tok,
                                  const float* __restrict__ table,
                                  const float* __restrict__ mask,
                                  u16* __restrict__ ebf) {
    int i = blockIdx.x * blockDim.x + threadIdx.x;   // float4 index
    const int n4 = NB * NE / 4;
    if (i >= n4) return;
    int b = i / (NE / 4);
    int c = i % (NE / 4);
    float4 t = ((const float4*)(table + (size_t)tok[b] * NE))[c];
    float4 m = ((const float4*)mask)[i];
    ushort4 o;
    o.x = f2bf(t.x * m.x); o.y = f2bf(t.y * m.y);
    o.z = f2bf(t.z * m.z); o.w = f2bf(t.w * m.w);
    ((ushort4*)ebf)[i] = o;
}

// ---------------------------------------------------------------------------
// LIF recurrence -> hsum = mask_lif * sum_t spike_t, output bf16
// ---------------------------------------------------------------------------
__global__ void lif_bf16_kernel(const float* __restrict__ delta1,
                                const float* __restrict__ hidden,
                                const float* __restrict__ mask_lif,
                                const float* __restrict__ thr_p,
                                const float* __restrict__ leak_p,
                                u16* __restrict__ hbf) {
    int i = blockIdx.x * blockDim.x + threadIdx.x;
    if (i >= NB * NH / 4) return;
    const float thr = thr_p[0];
    const float leak = leak_p[0];
    float4 d4 = ((const float4*)delta1)[i];
    float4 m4 = ((const float4*)hidden)[i];
    float4 k4 = ((const float4*)mask_lif)[i];
    float dd[4] = {d4.x, d4.y, d4.z, d4.w};
    float mm[4] = {m4.x, m4.y, m4.z, m4.w};
    float kk[4] = {k4.x, k4.y, k4.z, k4.w};
    ushort4 o;
    u16 oo[4];
#pragma unroll
    for (int j = 0; j < 4; ++j) {
        float m = mm[j], cnt = 0.0f;
#pragma unroll
        for (int t = 0; t < TSTEPS; ++t) {
            float mem = leak * m + dd[j];
            float s = ((mem / thr - 1.0f) > 0.0f) ? 1.0f : 0.0f;
            m = mem - thr * s;
            cnt += s;
        }
        oo[j] = f2bf(cnt * kk[j]);
    }
    o.x = oo[0]; o.y = oo[1]; o.z = oo[2]; o.w = oo[3];
    ((ushort4*)hbf)[i] = o;
}

// ---------------------------------------------------------------------------
// bf16 x bf16 MFMA GEMM (m97/round-2 skeleton): C = A*B^T + bias*scale
// A: bf16 [M,K], B: bf16 [N,K], both staged via global_load_lds width-16.
// Fragment-linear LDS: 1KB "units" of 16 rows x 32 k in MFMA lane order
// (lane l -> row l&15, k (l>>4)*8), so fragment ds_read_b128 at
// unit_base + l*16B is conflict-free (verified: SQ_LDS_BANK_CONFLICT=0).
// 2-barrier K-loop: stage -> sync (vmcnt drain) -> ds_read + 16 MFMA -> sync.
// This exact structure measured ~770-912 TF MFMA throughput (round 2 /
// learn_hip m97). Single-buffer LDS = 16 KB @128^2 -> 4 blocks/CU.
// Optional bf16 mirror output Cb. M % TBM == 0, K % 32 == 0; N edge
// clamped (loads) / guarded (stores).
// NOTE: concrete __global__ wrappers (template __global__ fails to link).
// ---------------------------------------------------------------------------
template<int TBM, int TBN, int NWAVE>
__device__ __forceinline__
void gemm_bb_body(const u16* __restrict__ Abf, const u16* __restrict__ Bbf,
                  const float* __restrict__ bias, float bias_scale,
                  float* __restrict__ C, u16* __restrict__ Cb,
                  int M, int N, int K) {
    constexpr int AU = TBM / 16;            // A units (1KB each)
    constexpr int BU = TBN / 16;
    constexpr int TOT = AU + BU;
    constexpr int PER = TOT / NWAVE;        // units staged per wave
    constexpr int WCN = TBN / 64;           // wave-columns
    static_assert(TOT % NWAVE == 0, "unit split");
    static_assert((TBM / 64) * WCN == NWAVE, "wave tiling");

    __shared__ u16 sA[TBM * 32];
    __shared__ u16 sB[TBN * 32];

    const int tid = threadIdx.x;
    const int w = tid >> 6;
    const int l = tid & 63;
    const int bm = blockIdx.y * TBM;
    const int bn = blockIdx.x * TBN;
    const int wr16 = (w / WCN) * 4;         // wave's A unit base
    const int wc16 = (w % WCN) * 4;         // wave's B unit base
    const int lrow = l & 15;                // staging row within unit
    const int lk8 = (l >> 4) * 8;           // staging k offset within BK=32
    const int l8 = l * 8;                   // fragment read offset (u16)

    f32x4 acc[4][4];
#pragma unroll
    for (int m = 0; m < 4; ++m)
#pragma unroll
        for (int n = 0; n < 4; ++n)
#pragma unroll
            for (int q = 0; q < 4; ++q) acc[m][n][q] = 0.0f;

    for (int k0 = 0; k0 < K; k0 += 32) {
        // stage: each wave loads PER units (A first, then B)
#pragma unroll
        for (int i = 0; i < PER; ++i) {
            const int c = w * PER + i;
            if (c < AU) {
                const int row = bm + c * 16 + lrow;
                __builtin_amdgcn_global_load_lds(Abf + (size_t)row * K + k0 + lk8,
                                                 &sA[c * 512], 16, 0, 0);
            } else {
                const int u = c - AU;
                int row = bn + u * 16 + lrow; if (row >= N) row = N - 1;
                __builtin_amdgcn_global_load_lds(Bbf + (size_t)row * K + k0 + lk8,
                                                 &sB[u * 512], 16, 0, 0);
            }
        }
        __syncthreads();

        bf16x8 ah[4], bh[4];
#pragma unroll
        for (int m = 0; m < 4; ++m)
            ah[m] = *(const bf16x8*)&sA[(wr16 + m) * 512 + l8];
#pragma unroll
        for (int n = 0; n < 4; ++n)
            bh[n] = *(const bf16x8*)&sB[(wc16 + n) * 512 + l8];

#pragma unroll
        for (int m = 0; m < 4; ++m)
#pragma unroll
            for (int n = 0; n < 4; ++n)
                acc[m][n] = __builtin_amdgcn_mfma_f32_16x16x32_bf16(ah[m], bh[n], acc[m][n], 0, 0, 0);
        __syncthreads();
    }

    // epilogue: C/D layout col = l&15, row = (l>>4)*4 + reg
    const int lq = (l >> 4) * 4;
    const int wrow = bm + (w / WCN) * 64;
    const int wcol = bn + (w % WCN) * 64;
#pragma unroll
    for (int n = 0; n < 4; ++n) {
        const int gcol = wcol + n * 16 + (l & 15);
        if (gcol >= N) continue;
        const float bb = bias[gcol] * bias_scale;
#pragma unroll
        for (int m = 0; m < 4; ++m) {
            const int grow = wrow + m * 16 + lq;
#pragma unroll
            for (int q = 0; q < 4; ++q) {
                float v = acc[m][n][q] + bb;
                C[(size_t)(grow + q) * N + gcol] = v;
                if (Cb) Cb[(size_t)(grow + q) * N + gcol] = f2bf(v);
            }
        }
    }
}

__global__ __launch_bounds__(256)
void gemm_bb_128(const u16* __restrict__ Abf, const u16* __restrict__ Bbf,
                 const float* __restrict__ bias, float bias_scale,
                 float* __restrict__ C, u16* __restrict__ Cb, int M, int N, int K) {
    gemm_bb_body<128, 128, 4>(Abf, Bbf, bias, bias_scale, C, Cb, M, N, K);
}

// ---------------------------------------------------------------------------
// fp32 fallback kernels (tiny-workspace safety net)
// ---------------------------------------------------------------------------
__global__ void embed_kernel(const int* __restrict__ tok,
                             const float* __restrict__ table,
                             const float* __restrict__ mask,
                             float* __restrict__ emb) {
    int i = blockIdx.x * blockDim.x + threadIdx.x;
    const int n4 = NB * NE / 4;
    if (i >= n4) return;
    int b = i / (NE / 4);
    int c = i % (NE / 4);
    float4 t = ((const float4*)(table + (size_t)tok[b] * NE))[c];
    float4 m = ((const float4*)mask)[i];
    float4 o;
    o.x = t.x * m.x; o.y = t.y * m.y; o.z = t.z * m.z; o.w = t.w * m.w;
    ((float4*)emb)[i] = o;
}

__global__ void lif_kernel(const float* __restrict__ delta1,
                           const float* __restrict__ hidden,
                           const float* __restrict__ mask_lif,
                           const float* __restrict__ thr_p,
                           const float* __restrict__ leak_p,
                           float* __restrict__ hsum) {
    int i = blockIdx.x * blockDim.x + threadIdx.x;
    if (i >= NB * NH) return;
    const float thr = thr_p[0];
    const float leak = leak_p[0];
    float d = delta1[i];
    float m = hidden[i];
    float cnt = 0.0f;
#pragma unroll
    for (int t = 0; t < TSTEPS; ++t) {
        float mem = leak * m + d;
        float s = ((mem / thr - 1.0f) > 0.0f) ? 1.0f : 0.0f;
        m = mem - thr * s;
        cnt += s;
    }
    hsum[i] = cnt * mask_lif[i];
}

#define BM 128
#define BN 128
#define BK 16

__global__ __launch_bounds__(256)
void gemm_nt(const float* __restrict__ A, const float* __restrict__ Bm,
             const float* __restrict__ bias, float bias_scale,
             float* __restrict__ C, int M, int N, int K) {
    __shared__ float As[BK][BM + 4];
    __shared__ float Bs[BK][BN + 4];

    const int tid = threadIdx.x;
    const int bm = blockIdx.y * BM;
    const int bn = blockIdx.x * BN;
    const int tx = tid & 15;
    const int ty = tid >> 4;
    const int tm = ty * 8;
    const int tn0 = tx * 4;
    const int tn1 = 64 + tx * 4;

    float acc[8][8];
#pragma unroll
    for (int i = 0; i < 8; ++i)
#pragma unroll
        for (int j = 0; j < 8; ++j) acc[i][j] = 0.0f;

    constexpr int LDA4 = BK / 4;

    for (int k0 = 0; k0 < K; k0 += BK) {
#pragma unroll
        for (int idx = tid; idx < BM * LDA4; idx += 256) {
            int m = idx / LDA4, c = idx % LDA4;
            float4 v = *(const float4*)(A + (size_t)(bm + m) * K + k0 + c * 4);
            As[c * 4 + 0][m] = v.x;
            As[c * 4 + 1][m] = v.y;
            As[c * 4 + 2][m] = v.z;
            As[c * 4 + 3][m] = v.w;
        }
#pragma unroll
        for (int idx = tid; idx < BN * LDA4; idx += 256) {
            int n = idx / LDA4, c = idx % LDA4;
            float4 v = make_float4(0.f, 0.f, 0.f, 0.f);
            int gn = bn + n;
            if (gn < N) v = *(const float4*)(Bm + (size_t)gn * K + k0 + c * 4);
            Bs[c * 4 + 0][n] = v.x;
            Bs[c * 4 + 1][n] = v.y;
            Bs[c * 4 + 2][n] = v.z;
            Bs[c * 4 + 3][n] = v.w;
        }
        __syncthreads();

#pragma unroll
        for (int k = 0; k < BK; ++k) {
            float4 a0 = *(const float4*)&As[k][tm];
            float4 a1 = *(const float4*)&As[k][tm + 4];
            float4 b0 = *(const float4*)&Bs[k][tn0];
            float4 b1 = *(const float4*)&Bs[k][tn1];
            float a[8] = {a0.x, a0.y, a0.z, a0.w, a1.x, a1.y, a1.z, a1.w};
            float bb[8] = {b0.x, b0.y, b0.z, b0.w, b1.x, b1.y, b1.z, b1.w};
#pragma unroll
            for (int i = 0; i < 8; ++i)
#pragma unroll
                for (int j = 0; j < 8; ++j)
                    acc[i][j] = fmaf(a[i], bb[j], acc[i][j]);
        }
        __syncthreads();
    }

#pragma unroll
    for (int i = 0; i < 8; ++i) {
        size_t row = (size_t)(bm + tm + i) * N;
#pragma unroll
        for (int j = 0; j < 8; ++j) {
            int gn = bn + ((j < 4) ? (tn0 + j) : (tn1 + j - 4));
            if (gn < N)
                C[row + gn] = acc[i][j] + bias[gn] * bias_scale;
        }
    }
}

// ---------------------------------------------------------------------------
extern "C" void kernel_launch(void* const* d_in, const int* in_sizes, int n_in,
                              void* d_out, int out_size, void* d_ws, size_t ws_size,
                              hipStream_t stream) {
    const int*   tok      = (const int*)  d_in[0];
    const float* hidden   = (const float*)d_in[1];
    const float* table    = (const float*)d_in[2];
    const float* W1       = (const float*)d_in[3];
    const float* b1       = (const float*)d_in[4];
    const float* W2       = (const float*)d_in[5];
    const float* b2       = (const float*)d_in[6];
    const float* fc_W     = (const float*)d_in[7];
    const float* fc_b     = (const float*)d_in[8];
    const float* thr      = (const float*)d_in[9];
    const float* leak     = (const float*)d_in[10];
    const float* mask_emb = (const float*)d_in[11];
    const float* mask_lif = (const float*)d_in[12];

    float* linear = (float*)d_out;                   // [B,V]
    float* outbuf = (float*)d_out + (size_t)NB * NV; // [B,H]

    const size_t SZ_EB  = (size_t)NB * NE * 2;   // ebf
    const size_t SZ_D1  = (size_t)NB * NH * 4;   // delta1 fp32
    const size_t SZ_HB  = (size_t)NB * NH * 2;   // hbf
    const size_t SZ_OB  = (size_t)NB * NH * 2;   // obf
    const size_t SZ_W1B = (size_t)NH * NE * 2;   // W1 bf16
    const size_t SZ_W2B = (size_t)NH * NH * 2;   // W2 bf16
    const size_t SZ_WB  = (size_t)NV * NH * 2;   // fc_W bf16 (~103 MB)
    const size_t need_bf = SZ_EB + SZ_D1 + SZ_HB + SZ_OB + SZ_W1B + SZ_W2B + SZ_WB;

    char* p = (char*)d_ws;

    if (ws_size >= need_bf) {
        u16*   ebf    = (u16*)p;   p += SZ_EB;
        float* delta1 = (float*)p; p += SZ_D1;
        u16*   hbf    = (u16*)p;   p += SZ_HB;
        u16*   obf    = (u16*)p;   p += SZ_OB;
        u16*   w1b    = (u16*)p;   p += SZ_W1B;
        u16*   w2b    = (u16*)p;   p += SZ_W2B;
        u16*   fcwb   = (u16*)p;   p += SZ_WB;

        // weight converts (fc_W dominates: ~310 MB traffic, HBM-bound)
        cvt_bf16_kernel<<<2048, 256, 0, stream>>>(fc_W, fcwb, NV * NH / 4);
        cvt_bf16_kernel<<<512, 256, 0, stream>>>(W1, w1b, NH * NE / 4);
        cvt_bf16_kernel<<<512, 256, 0, stream>>>(W2, w2b, NH * NH / 4);
        // 0: embedding gather + mask -> bf16
        {
            int n4 = NB * NE / 4;
            embed_bf16_kernel<<<(n4 + 255) / 256, 256, 0, stream>>>(tok, table, mask_emb, ebf);
        }
        // 1: delta1 = ebf @ w1b^T + b1   (M=B, N=H, K=E)
        {
            dim3 grid(NH / 128, NB / 128);
            gemm_bb_128<<<grid, 256, 0, stream>>>(ebf, w1b, b1, 1.0f,
                                                  delta1, (u16*)nullptr, NB, NH, NE);
        }
        // 2: LIF -> hbf (bf16)
        {
            int n = NB * NH / 4;
            lif_bf16_kernel<<<(n + 255) / 256, 256, 0, stream>>>(delta1, hidden, mask_lif,
                                                                 thr, leak, hbf);
        }
        // 3: out = hbf @ w2b^T + 10*b2 -> outbuf (fp32) + obf (bf16)
        {
            dim3 grid(NH / 128, NB / 128);
            gemm_bb_128<<<grid, 256, 0, stream>>>(hbf, w2b, b2, (float)TSTEPS,
                                                  outbuf, obf, NB, NH, NH);
        }
        // 4: linear = obf @ fcwb^T + fc_b  (M=B, N=V, K=H)
        {
            dim3 grid((NV + 127) / 128, NB / 128);
            gemm_bb_128<<<grid, 256, 0, stream>>>(obf, fcwb, fc_b, 1.0f,
                                                  linear, (u16*)nullptr, NB, NV, NH);
        }
    } else {
        // ----- pure fp32 fallback -----
        float* emb    = (float*)p;  p += (size_t)NB * NE * 4;
        float* delta1 = (float*)p;  p += SZ_D1;
        float* hsum   = (float*)p;

        int n4 = NB * NE / 4;
        embed_kernel<<<(n4 + 255) / 256, 256, 0, stream>>>(tok, table, mask_emb, emb);
        {
            dim3 grid(NH / BN, NB / BM);
            gemm_nt<<<grid, 256, 0, stream>>>(emb, W1, b1, 1.0f, delta1, NB, NH, NE);
        }
        {
            int n = NB * NH;
            lif_kernel<<<(n + 255) / 256, 256, 0, stream>>>(delta1, hidden, mask_lif,
                                                            thr, leak, hsum);
        }
        {
            dim3 grid(NH / BN, NB / BM);
            gemm_nt<<<grid, 256, 0, stream>>>(hsum, W2, b2, (float)TSTEPS, outbuf, NB, NH, NH);
        }
        {
            dim3 grid((NV + BN - 1) / BN, NB / BM);
            gemm_nt<<<grid, 256, 0, stream>>>(outbuf, fc_W, fc_b, 1.0f, linear, NB, NV, NH);
        }
    }
}

// Round 8
// 401.607 us; speedup vs baseline: 3.1792x; 1.0113x over previous
//
#include <hip/hip_runtime.h>

#define NV 50257
#define NE 512
#define NH 1024
#define NB 1024
#define TSTEPS 10

typedef __bf16 bf16x8 __attribute__((ext_vector_type(8)));
typedef float  f32x4  __attribute__((ext_vector_type(4)));
typedef unsigned short u16;

// fp32 -> bf16 round-to-nearest-even
__device__ __forceinline__ u16 f2bf(float v) {
    unsigned u = __float_as_uint(v);
    unsigned r = u + 0x7fffu + ((u >> 16) & 1u);
    return (u16)(r >> 16);
}

// ---------------------------------------------------------------------------
// streaming fp32 -> bf16 convert (fc_W, W1, W2)
// ---------------------------------------------------------------------------
__global__ void cvt_bf16_kernel(const float* __restrict__ x,
                                u16* __restrict__ y, int n4) {
    int i0 = blockIdx.x * blockDim.x + threadIdx.x;
    int stride = gridDim.x * blockDim.x;
    for (int i = i0; i < n4; i += stride) {
        float4 v = ((const float4*)x)[i];
        ushort4 o;
        o.x = f2bf(v.x); o.y = f2bf(v.y); o.z = f2bf(v.z); o.w = f2bf(v.w);
        ((ushort4*)y)[i] = o;
    }
}

// ---------------------------------------------------------------------------
// embedding gather + dropout mask -> bf16
// ---------------------------------------------------------------------------
__global__ void embed_bf16_kernel(const int* __restrict__ tok,
                                  const float* __restrict__ table,
                                  const float* __restrict__ mask,
                                  u16* __restrict__ ebf) {
    int i = blockIdx.x * blockDim.x + threadIdx.x;   // float4 index
    const int n4 = NB * NE / 4;
    if (i >= n4) return;
    int b = i / (NE / 4);
    int c = i % (NE / 4);
    float4 t = ((const float4*)(table + (size_t)tok[b] * NE))[c];
    float4 m = ((const float4*)mask)[i];
    ushort4 o;
    o.x = f2bf(t.x * m.x); o.y = f2bf(t.y * m.y);
    o.z = f2bf(t.z * m.z); o.w = f2bf(t.w * m.w);
    ((ushort4*)ebf)[i] = o;
}

// ---------------------------------------------------------------------------
// LIF recurrence -> hsum = mask_lif * sum_t spike_t, output bf16
// ---------------------------------------------------------------------------
__global__ void lif_bf16_kernel(const float* __restrict__ delta1,
                                const float* __restrict__ hidden,
                                const float* __restrict__ mask_lif,
                                const float* __restrict__ thr_p,
                                const float* __restrict__ leak_p,
                                u16* __restrict__ hbf) {
    int i = blockIdx.x * blockDim.x + threadIdx.x;
    if (i >= NB * NH / 4) return;
    const float thr = thr_p[0];
    const float leak = leak_p[0];
    float4 d4 = ((const float4*)delta1)[i];
    float4 m4 = ((const float4*)hidden)[i];
    float4 k4 = ((const float4*)mask_lif)[i];
    float dd[4] = {d4.x, d4.y, d4.z, d4.w};
    float mm[4] = {m4.x, m4.y, m4.z, m4.w};
    float kk[4] = {k4.x, k4.y, k4.z, k4.w};
    ushort4 o;
    u16 oo[4];
#pragma unroll
    for (int j = 0; j < 4; ++j) {
        float m = mm[j], cnt = 0.0f;
#pragma unroll
        for (int t = 0; t < TSTEPS; ++t) {
            float mem = leak * m + dd[j];
            float s = ((mem / thr - 1.0f) > 0.0f) ? 1.0f : 0.0f;
            m = mem - thr * s;
            cnt += s;
        }
        oo[j] = f2bf(cnt * kk[j]);
    }
    o.x = oo[0]; o.y = oo[1]; o.z = oo[2]; o.w = oo[3];
    ((ushort4*)hbf)[i] = o;
}

// ---------------------------------------------------------------------------
// bf16 x bf16 MFMA GEMM, pipelined with counted vmcnt (T3+T4):
//   C = A*B^T + bias*scale
// - Fragment-linear LDS: 1KB "units" of 16 rows x 32 k in MFMA lane order
//   (lane l -> row l&15, k (l>>4)*8); fragment ds_read_b128 at
//   unit_base + l*16B is conflict-free (measured SQ_LDS_BANK_CONFLICT=0).
// - DEPTH=4 buffers (64 KB), issue-ahead=2. Per K-step:
//     s_waitcnt vmcnt(PER)   [tail: vmcnt(0) on last iter  <- round-7 race fix]
//     sched_barrier; s_barrier; sched_barrier
//     stage(t+2)             // counted prefetch, never drained mid-loop
//     ds_read buf t -> 16 MFMA
//     sched_barrier          // nothing crosses the iteration boundary
//   vmcnt correctness: at the wait, a wave has stages t (PER loads) and t+1
//   (PER loads) outstanding; vmcnt(PER) completes the PER oldest = stage t.
//   Last iter has only stage NT-1 outstanding -> must be vmcnt(0) (this was
//   the round-7 nondeterminism: vmcnt(8) was a no-op at the tail).
//   WAR safety: stage(t+2) writes a buffer last READ at iter t-2 — three
//   barriers of separation; sched_barrier(0) fences stop ds/MFMA migration.
// - blockIdx.x = ROW block (fastest): row-blocks sharing a B panel run
//   concurrently -> B fetched ~once from HBM instead of M/TBM times.
// Requires M % TBM == 0, K % 32 == 0, K/32 >= 2. N edge clamped/guarded.
// NOTE: concrete __global__ wrappers (template __global__ fails to link).
// ---------------------------------------------------------------------------
template<int TBM, int TBN, int NWAVE>
__device__ __forceinline__
void gemm_pipe_body(const u16* __restrict__ Abf, const u16* __restrict__ Bbf,
                    const float* __restrict__ bias, float bias_scale,
                    float* __restrict__ C, u16* __restrict__ Cb,
                    int M, int N, int K) {
    constexpr int AU = TBM / 16;            // A units (1KB each)
    constexpr int BU = TBN / 16;
    constexpr int TOT = AU + BU;
    constexpr int PER = TOT / NWAVE;        // gload_lds per wave per stage
    constexpr int WCN = TBN / 64;           // wave-columns
    constexpr int DEPTH = 4;
    static_assert(TOT % NWAVE == 0, "unit split");
    static_assert((TBM / 64) * WCN == NWAVE, "wave tiling");

    __shared__ u16 sA[DEPTH][AU * 512];
    __shared__ u16 sB[DEPTH][BU * 512];

    const int tid = threadIdx.x;
    const int w = tid >> 6;
    const int l = tid & 63;
    const int bm = blockIdx.x * TBM;        // row block = fastest dim
    const int bn = blockIdx.y * TBN;
    const int wr16 = (w / WCN) * 4;         // wave's A unit base
    const int wc16 = (w % WCN) * 4;         // wave's B unit base
    const int lrow = l & 15;                // staging row within unit
    const int lk8 = (l >> 4) * 8;           // staging k offset within BK=32
    const int l8 = l * 8;                   // fragment read offset (u16)

    f32x4 acc[4][4];
#pragma unroll
    for (int m = 0; m < 4; ++m)
#pragma unroll
        for (int n = 0; n < 4; ++n)
#pragma unroll
            for (int q = 0; q < 4; ++q) acc[m][n][q] = 0.0f;

    const int NT = K / 32;

    auto stage = [&](int buf, int k0) {
#pragma unroll
        for (int i = 0; i < PER; ++i) {
            const int c = w * PER + i;
            if (c < AU) {
                const int row = bm + c * 16 + lrow;
                __builtin_amdgcn_global_load_lds(Abf + (size_t)row * K + k0 + lk8,
                                                 &sA[buf][c * 512], 16, 0, 0);
            } else {
                const int u = c - AU;
                int row = bn + u * 16 + lrow; if (row >= N) row = N - 1;
                __builtin_amdgcn_global_load_lds(Bbf + (size_t)row * K + k0 + lk8,
                                                 &sB[buf][u * 512], 16, 0, 0);
            }
        }
    };

    // prologue: 2 stages in flight
    stage(0, 0);
    stage(1, 32);

    for (int t = 0; t < NT; ++t) {
        // complete stage t (own loads), then rendezvous.
        if (t + 1 < NT) {
            asm volatile("s_waitcnt vmcnt(%0)" :: "n"(PER) : "memory");
        } else {
            asm volatile("s_waitcnt vmcnt(0)" ::: "memory");   // tail drain
        }
        __builtin_amdgcn_sched_barrier(0);
        __builtin_amdgcn_s_barrier();
        __builtin_amdgcn_sched_barrier(0);

        if (t + 2 < NT) stage((t + 2) & (DEPTH - 1), (t + 2) * 32);

        const int cb = t & (DEPTH - 1);
        bf16x8 ah[4], bh[4];
#pragma unroll
        for (int m = 0; m < 4; ++m)
            ah[m] = *(const bf16x8*)&sA[cb][(wr16 + m) * 512 + l8];
#pragma unroll
        for (int n = 0; n < 4; ++n)
            bh[n] = *(const bf16x8*)&sB[cb][(wc16 + n) * 512 + l8];

#pragma unroll
        for (int m = 0; m < 4; ++m)
#pragma unroll
            for (int n = 0; n < 4; ++n)
                acc[m][n] = __builtin_amdgcn_mfma_f32_16x16x32_bf16(ah[m], bh[n], acc[m][n], 0, 0, 0);

        __builtin_amdgcn_sched_barrier(0);   // pin body inside the iteration
    }

    // epilogue: C/D layout col = l&15, row = (l>>4)*4 + reg
    const int lq = (l >> 4) * 4;
    const int wrow = bm + (w / WCN) * 64;
    const int wcol = bn + (w % WCN) * 64;
#pragma unroll
    for (int n = 0; n < 4; ++n) {
        const int gcol = wcol + n * 16 + (l & 15);
        if (gcol >= N) continue;
        const float bb = bias[gcol] * bias_scale;
#pragma unroll
        for (int m = 0; m < 4; ++m) {
            const int grow = wrow + m * 16 + lq;
#pragma unroll
            for (int q = 0; q < 4; ++q) {
                float v = acc[m][n][q] + bb;
                C[(size_t)(grow + q) * N + gcol] = v;
                if (Cb) Cb[(size_t)(grow + q) * N + gcol] = f2bf(v);
            }
        }
    }
}

__global__ __launch_bounds__(256)
void gemm_pipe_128(const u16* __restrict__ Abf, const u16* __restrict__ Bbf,
                   const float* __restrict__ bias, float bias_scale,
                   float* __restrict__ C, u16* __restrict__ Cb, int M, int N, int K) {
    gemm_pipe_body<128, 128, 4>(Abf, Bbf, bias, bias_scale, C, Cb, M, N, K);
}

// ---------------------------------------------------------------------------
// fp32 fallback kernels (tiny-workspace safety net)
// ---------------------------------------------------------------------------
__global__ void embed_kernel(const int* __restrict__ tok,
                             const float* __restrict__ table,
                             const float* __restrict__ mask,
                             float* __restrict__ emb) {
    int i = blockIdx.x * blockDim.x + threadIdx.x;
    const int n4 = NB * NE / 4;
    if (i >= n4) return;
    int b = i / (NE / 4);
    int c = i % (NE / 4);
    float4 t = ((const float4*)(table + (size_t)tok[b] * NE))[c];
    float4 m = ((const float4*)mask)[i];
    float4 o;
    o.x = t.x * m.x; o.y = t.y * m.y; o.z = t.z * m.z; o.w = t.w * m.w;
    ((float4*)emb)[i] = o;
}

__global__ void lif_kernel(const float* __restrict__ delta1,
                           const float* __restrict__ hidden,
                           const float* __restrict__ mask_lif,
                           const float* __restrict__ thr_p,
                           const float* __restrict__ leak_p,
                           float* __restrict__ hsum) {
    int i = blockIdx.x * blockDim.x + threadIdx.x;
    if (i >= NB * NH) return;
    const float thr = thr_p[0];
    const float leak = leak_p[0];
    float d = delta1[i];
    float m = hidden[i];
    float cnt = 0.0f;
#pragma unroll
    for (int t = 0; t < TSTEPS; ++t) {
        float mem = leak * m + d;
        float s = ((mem / thr - 1.0f) > 0.0f) ? 1.0f : 0.0f;
        m = mem - thr * s;
        cnt += s;
    }
    hsum[i] = cnt * mask_lif[i];
}

#define BM 128
#define BN 128
#define BK 16

__global__ __launch_bounds__(256)
void gemm_nt(const float* __restrict__ A, const float* __restrict__ Bm,
             const float* __restrict__ bias, float bias_scale,
             float* __restrict__ C, int M, int N, int K) {
    __shared__ float As[BK][BM + 4];
    __shared__ float Bs[BK][BN + 4];

    const int tid = threadIdx.x;
    const int bm = blockIdx.y * BM;
    const int bn = blockIdx.x * BN;
    const int tx = tid & 15;
    const int ty = tid >> 4;
    const int tm = ty * 8;
    const int tn0 = tx * 4;
    const int tn1 = 64 + tx * 4;

    float acc[8][8];
#pragma unroll
    for (int i = 0; i < 8; ++i)
#pragma unroll
        for (int j = 0; j < 8; ++j) acc[i][j] = 0.0f;

    constexpr int LDA4 = BK / 4;

    for (int k0 = 0; k0 < K; k0 += BK) {
#pragma unroll
        for (int idx = tid; idx < BM * LDA4; idx += 256) {
            int m = idx / LDA4, c = idx % LDA4;
            float4 v = *(const float4*)(A + (size_t)(bm + m) * K + k0 + c * 4);
            As[c * 4 + 0][m] = v.x;
            As[c * 4 + 1][m] = v.y;
            As[c * 4 + 2][m] = v.z;
            As[c * 4 + 3][m] = v.w;
        }
#pragma unroll
        for (int idx = tid; idx < BN * LDA4; idx += 256) {
            int n = idx / LDA4, c = idx % LDA4;
            float4 v = make_float4(0.f, 0.f, 0.f, 0.f);
            int gn = bn + n;
            if (gn < N) v = *(const float4*)(Bm + (size_t)gn * K + k0 + c * 4);
            Bs[c * 4 + 0][n] = v.x;
            Bs[c * 4 + 1][n] = v.y;
            Bs[c * 4 + 2][n] = v.z;
            Bs[c * 4 + 3][n] = v.w;
        }
        __syncthreads();

#pragma unroll
        for (int k = 0; k < BK; ++k) {
            float4 a0 = *(const float4*)&As[k][tm];
            float4 a1 = *(const float4*)&As[k][tm + 4];
            float4 b0 = *(const float4*)&Bs[k][tn0];
            float4 b1 = *(const float4*)&Bs[k][tn1];
            float a[8] = {a0.x, a0.y, a0.z, a0.w, a1.x, a1.y, a1.z, a1.w};
            float bb[8] = {b0.x, b0.y, b0.z, b0.w, b1.x, b1.y, b1.z, b1.w};
#pragma unroll
            for (int i = 0; i < 8; ++i)
#pragma unroll
                for (int j = 0; j < 8; ++j)
                    acc[i][j] = fmaf(a[i], bb[j], acc[i][j]);
        }
        __syncthreads();
    }

#pragma unroll
    for (int i = 0; i < 8; ++i) {
        size_t row = (size_t)(bm + tm + i) * N;
#pragma unroll
        for (int j = 0; j < 8; ++j) {
            int gn = bn + ((j < 4) ? (tn0 + j) : (tn1 + j - 4));
            if (gn < N)
                C[row + gn] = acc[i][j] + bias[gn] * bias_scale;
        }
    }
}

// ---------------------------------------------------------------------------
extern "C" void kernel_launch(void* const* d_in, const int* in_sizes, int n_in,
                              void* d_out, int out_size, void* d_ws, size_t ws_size,
                              hipStream_t stream) {
    const int*   tok      = (const int*)  d_in[0];
    const float* hidden   = (const float*)d_in[1];
    const float* table    = (const float*)d_in[2];
    const float* W1       = (const float*)d_in[3];
    const float* b1       = (const float*)d_in[4];
    const float* W2       = (const float*)d_in[5];
    const float* b2       = (const float*)d_in[6];
    const float* fc_W     = (const float*)d_in[7];
    const float* fc_b     = (const float*)d_in[8];
    const float* thr      = (const float*)d_in[9];
    const float* leak     = (const float*)d_in[10];
    const float* mask_emb = (const float*)d_in[11];
    const float* mask_lif = (const float*)d_in[12];

    float* linear = (float*)d_out;                   // [B,V]
    float* outbuf = (float*)d_out + (size_t)NB * NV; // [B,H]

    const size_t SZ_EB  = (size_t)NB * NE * 2;   // ebf
    const size_t SZ_D1  = (size_t)NB * NH * 4;   // delta1 fp32
    const size_t SZ_HB  = (size_t)NB * NH * 2;   // hbf
    const size_t SZ_OB  = (size_t)NB * NH * 2;   // obf
    const size_t SZ_W1B = (size_t)NH * NE * 2;   // W1 bf16
    const size_t SZ_W2B = (size_t)NH * NH * 2;   // W2 bf16
    const size_t SZ_WB  = (size_t)NV * NH * 2;   // fc_W bf16 (~103 MB)
    const size_t need_bf = SZ_EB + SZ_D1 + SZ_HB + SZ_OB + SZ_W1B + SZ_W2B + SZ_WB;

    char* p = (char*)d_ws;

    if (ws_size >= need_bf) {
        u16*   ebf    = (u16*)p;   p += SZ_EB;
        float* delta1 = (float*)p; p += SZ_D1;
        u16*   hbf    = (u16*)p;   p += SZ_HB;
        u16*   obf    = (u16*)p;   p += SZ_OB;
        u16*   w1b    = (u16*)p;   p += SZ_W1B;
        u16*   w2b    = (u16*)p;   p += SZ_W2B;
        u16*   fcwb   = (u16*)p;   p += SZ_WB;

        // weight converts (fc_W dominates: ~310 MB traffic, HBM-bound)
        cvt_bf16_kernel<<<2048, 256, 0, stream>>>(fc_W, fcwb, NV * NH / 4);
        cvt_bf16_kernel<<<512, 256, 0, stream>>>(W1, w1b, NH * NE / 4);
        cvt_bf16_kernel<<<512, 256, 0, stream>>>(W2, w2b, NH * NH / 4);
        // 0: embedding gather + mask -> bf16
        {
            int n4 = NB * NE / 4;
            embed_bf16_kernel<<<(n4 + 255) / 256, 256, 0, stream>>>(tok, table, mask_emb, ebf);
        }
        // 1: delta1 = ebf @ w1b^T + b1   (M=B, N=H, K=E)
        {
            dim3 grid(NB / 128, NH / 128);   // x = row block
            gemm_pipe_128<<<grid, 256, 0, stream>>>(ebf, w1b, b1, 1.0f,
                                                    delta1, (u16*)nullptr, NB, NH, NE);
        }
        // 2: LIF -> hbf (bf16)
        {
            int n = NB * NH / 4;
            lif_bf16_kernel<<<(n + 255) / 256, 256, 0, stream>>>(delta1, hidden, mask_lif,
                                                                 thr, leak, hbf);
        }
        // 3: out = hbf @ w2b^T + 10*b2 -> outbuf (fp32) + obf (bf16)
        {
            dim3 grid(NB / 128, NH / 128);
            gemm_pipe_128<<<grid, 256, 0, stream>>>(hbf, w2b, b2, (float)TSTEPS,
                                                    outbuf, obf, NB, NH, NH);
        }
        // 4: linear = obf @ fcwb^T + fc_b  (M=B, N=V, K=H)
        {
            dim3 grid(NB / 128, (NV + 127) / 128);
            gemm_pipe_128<<<grid, 256, 0, stream>>>(obf, fcwb, fc_b, 1.0f,
                                                    linear, (u16*)nullptr, NB, NV, NH);
        }
    } else {
        // ----- pure fp32 fallback -----
        float* emb    = (float*)p;  p += (size_t)NB * NE * 4;
        float* delta1 = (float*)p;  p += SZ_D1;
        float* hsum   = (float*)p;

        int n4 = NB * NE / 4;
        embed_kernel<<<(n4 + 255) / 256, 256, 0, stream>>>(tok, table, mask_emb, emb);
        {
            dim3 grid(NH / BN, NB / BM);
            gemm_nt<<<grid, 256, 0, stream>>>(emb, W1, b1, 1.0f, delta1, NB, NH, NE);
        }
        {
            int n = NB * NH;
            lif_kernel<<<(n + 255) / 256, 256, 0, stream>>>(delta1, hidden, mask_lif,
                                                            thr, leak, hsum);
        }
        {
            dim3 grid(NH / BN, NB / BM);
            gemm_nt<<<grid, 256, 0, stream>>>(hsum, W2, b2, (float)TSTEPS, outbuf, NB, NH, NH);
        }
        {
            dim3 grid((NV + BN - 1) / BN, NB / BM);
            gemm_nt<<<grid, 256, 0, stream>>>(outbuf, fc_W, fc_b, 1.0f, linear, NB, NV, NH);
        }
    }
}

// Round 9
// 351.066 us; speedup vs baseline: 3.6369x; 1.1440x over previous
//
#include <hip/hip_runtime.h>

#define NV 50257
#define NE 512
#define NH 1024
#define NB 1024
#define TSTEPS 10

typedef __bf16 bf16x8 __attribute__((ext_vector_type(8)));
typedef float  f32x4  __attribute__((ext_vector_type(4)));
typedef unsigned short u16;

// fp32 -> bf16 round-to-nearest-even
__device__ __forceinline__ u16 f2bf(float v) {
    unsigned u = __float_as_uint(v);
    unsigned r = u + 0x7fffu + ((u >> 16) & 1u);
    return (u16)(r >> 16);
}

// ---------------------------------------------------------------------------
// streaming fp32 -> bf16 convert (fc_W, W1, W2)
// ---------------------------------------------------------------------------
__global__ void cvt_bf16_kernel(const float* __restrict__ x,
                                u16* __restrict__ y, int n4) {
    int i0 = blockIdx.x * blockDim.x + threadIdx.x;
    int stride = gridDim.x * blockDim.x;
    for (int i = i0; i < n4; i += stride) {
        float4 v = ((const float4*)x)[i];
        ushort4 o;
        o.x = f2bf(v.x); o.y = f2bf(v.y); o.z = f2bf(v.z); o.w = f2bf(v.w);
        ((ushort4*)y)[i] = o;
    }
}

// ---------------------------------------------------------------------------
// embedding gather + dropout mask -> bf16
// ---------------------------------------------------------------------------
__global__ void embed_bf16_kernel(const int* __restrict__ tok,
                                  const float* __restrict__ table,
                                  const float* __restrict__ mask,
                                  u16* __restrict__ ebf) {
    int i = blockIdx.x * blockDim.x + threadIdx.x;   // float4 index
    const int n4 = NB * NE / 4;
    if (i >= n4) return;
    int b = i / (NE / 4);
    int c = i % (NE / 4);
    float4 t = ((const float4*)(table + (size_t)tok[b] * NE))[c];
    float4 m = ((const float4*)mask)[i];
    ushort4 o;
    o.x = f2bf(t.x * m.x); o.y = f2bf(t.y * m.y);
    o.z = f2bf(t.z * m.z); o.w = f2bf(t.w * m.w);
    ((ushort4*)ebf)[i] = o;
}

// ---------------------------------------------------------------------------
// LIF recurrence -> hsum = mask_lif * sum_t spike_t, output bf16
// ---------------------------------------------------------------------------
__global__ void lif_bf16_kernel(const float* __restrict__ delta1,
                                const float* __restrict__ hidden,
                                const float* __restrict__ mask_lif,
                                const float* __restrict__ thr_p,
                                const float* __restrict__ leak_p,
                                u16* __restrict__ hbf) {
    int i = blockIdx.x * blockDim.x + threadIdx.x;
    if (i >= NB * NH / 4) return;
    const float thr = thr_p[0];
    const float leak = leak_p[0];
    float4 d4 = ((const float4*)delta1)[i];
    float4 m4 = ((const float4*)hidden)[i];
    float4 k4 = ((const float4*)mask_lif)[i];
    float dd[4] = {d4.x, d4.y, d4.z, d4.w};
    float mm[4] = {m4.x, m4.y, m4.z, m4.w};
    float kk[4] = {k4.x, k4.y, k4.z, k4.w};
    ushort4 o;
    u16 oo[4];
#pragma unroll
    for (int j = 0; j < 4; ++j) {
        float m = mm[j], cnt = 0.0f;
#pragma unroll
        for (int t = 0; t < TSTEPS; ++t) {
            float mem = leak * m + dd[j];
            float s = ((mem / thr - 1.0f) > 0.0f) ? 1.0f : 0.0f;
            m = mem - thr * s;
            cnt += s;
        }
        oo[j] = f2bf(cnt * kk[j]);
    }
    o.x = oo[0]; o.y = oo[1]; o.z = oo[2]; o.w = oo[3];
    ((ushort4*)hbf)[i] = o;
}

// ---------------------------------------------------------------------------
// bf16 x bf16 MFMA GEMM v2: wave-tile 64 x (TBN/2), counted-vmcnt pipeline,
// XCD-grouped 1D grid.  C = A*B^T + bias*scale.
// - Per-wave MFMA per K-step = 4 * (TBN/32): TBN=256 -> 32 MFMA = 515 cy of
//   matrix-pipe work per barrier (round-2's amortization lever, 2x round 6/8).
// - Fragment-linear LDS (1KB units, lane l -> row l&15, k (l>>4)*8):
//   conflict-free ds_read_b128 (measured SQ_LDS_BANK_CONFLICT = 0).
// - DEPTH=3 x 24KB (TBN=256) = 72 KB -> 2 blocks/CU; round-8-proven sync:
//   vmcnt(PER) steady / vmcnt(0) last iter, one s_barrier per step,
//   stage(t+2) writes the buffer last read at t-1 (barrier-separated;
//   sched_barrier(0) fences pin the body).
// - XCD grouping: 1D grid, x=i&7, r=(i>>3)&7, p=((i>>6)<<3)+x. All 8
//   row-blocks of col-panel p have dispatch index == p (mod 8) -> same XCD
//   (round-robin heuristic) -> B panel fetched once per XCD L2, not 8x.
//   Bijective on padded grid (panels >= P return early). REQUIRES M/TBM == 8.
// Requires K % 32 == 0, K/32 >= 2. N edge clamped (loads) / guarded (stores).
// NOTE: concrete __global__ wrappers (template __global__ fails to link).
// ---------------------------------------------------------------------------
template<int TBM, int TBN, int NWAVE>
__device__ __forceinline__
void gemm_pipe2_body(const u16* __restrict__ Abf, const u16* __restrict__ Bbf,
                     const float* __restrict__ bias, float bias_scale,
                     float* __restrict__ C, u16* __restrict__ Cb,
                     int M, int N, int K) {
    constexpr int AU = TBM / 16;            // A units (1KB each)
    constexpr int BU = TBN / 16;
    constexpr int TOT = AU + BU;
    constexpr int PER = TOT / NWAVE;        // gload_lds per wave per stage
    constexpr int MF = 4;                   // m-frags per wave (wave rows = 64)
    constexpr int NF = TBN / 32;            // n-frags per wave (2 wave-cols)
    constexpr int DEPTH = 3;
    static_assert(TOT % NWAVE == 0, "unit split");
    static_assert(NWAVE == 4 && TBM == 128, "wave tiling: 2x2 waves, 64-row tiles");

    __shared__ u16 sA[DEPTH][AU * 512];
    __shared__ u16 sB[DEPTH][BU * 512];

    // XCD-grouped decode (requires exactly 8 row-blocks)
    const int i = blockIdx.x;
    const int xcd = i & 7;
    const int rb  = (i >> 3) & 7;
    const int p   = ((i >> 6) << 3) + xcd;
    if (p * TBN >= N) return;               // padded-grid guard (before barriers)
    const int bm = rb * TBM;
    const int bn = p * TBN;

    const int tid = threadIdx.x;
    const int w = tid >> 6;
    const int l = tid & 63;
    const int wr16 = (w >> 1) * MF;         // wave's A unit base
    const int wc16 = (w & 1) * NF;          // wave's B unit base
    const int lrow = l & 15;                // staging row within unit
    const int lk8 = (l >> 4) * 8;           // staging k offset within BK=32
    const int l8 = l * 8;                   // fragment read offset (u16)

    f32x4 acc[MF][NF];
#pragma unroll
    for (int m = 0; m < MF; ++m)
#pragma unroll
        for (int n = 0; n < NF; ++n)
#pragma unroll
            for (int q = 0; q < 4; ++q) acc[m][n][q] = 0.0f;

    const int NT = K / 32;

    auto stage = [&](int buf, int k0) {
#pragma unroll
        for (int s = 0; s < PER; ++s) {
            const int c = w * PER + s;
            if (c < AU) {
                const int row = bm + c * 16 + lrow;
                __builtin_amdgcn_global_load_lds(Abf + (size_t)row * K + k0 + lk8,
                                                 &sA[buf][c * 512], 16, 0, 0);
            } else {
                const int u = c - AU;
                int row = bn + u * 16 + lrow; if (row >= N) row = N - 1;
                __builtin_amdgcn_global_load_lds(Bbf + (size_t)row * K + k0 + lk8,
                                                 &sB[buf][u * 512], 16, 0, 0);
            }
        }
    };

    // prologue: 2 stages in flight
    stage(0, 0);
    stage(1, 32);

    int cur = 0;
    for (int t = 0; t < NT; ++t) {
        // complete stage t, keep stage t+1 in flight (tail: drain all)
        if (t + 1 < NT) {
            asm volatile("s_waitcnt vmcnt(%0)" :: "n"(PER) : "memory");
        } else {
            asm volatile("s_waitcnt vmcnt(0)" ::: "memory");
        }
        __builtin_amdgcn_sched_barrier(0);
        __builtin_amdgcn_s_barrier();
        __builtin_amdgcn_sched_barrier(0);

        if (t + 2 < NT) {
            int nb = cur + 2; if (nb >= DEPTH) nb -= DEPTH;
            stage(nb, (t + 2) * 32);
        }

        bf16x8 ah[MF], bh[NF];
#pragma unroll
        for (int m = 0; m < MF; ++m)
            ah[m] = *(const bf16x8*)&sA[cur][(wr16 + m) * 512 + l8];
#pragma unroll
        for (int n = 0; n < NF; ++n)
            bh[n] = *(const bf16x8*)&sB[cur][(wc16 + n) * 512 + l8];

#pragma unroll
        for (int m = 0; m < MF; ++m)
#pragma unroll
            for (int n = 0; n < NF; ++n)
                acc[m][n] = __builtin_amdgcn_mfma_f32_16x16x32_bf16(ah[m], bh[n], acc[m][n], 0, 0, 0);

        __builtin_amdgcn_sched_barrier(0);   // pin body inside the iteration
        cur = (cur + 1 == DEPTH) ? 0 : cur + 1;
    }

    // epilogue: C/D layout col = l&15, row = (l>>4)*4 + reg
    const int lq = (l >> 4) * 4;
    const int wrow = bm + (w >> 1) * 64;
    const int wcol = bn + (w & 1) * (NF * 16);
#pragma unroll
    for (int n = 0; n < NF; ++n) {
        const int gcol = wcol + n * 16 + (l & 15);
        if (gcol >= N) continue;
        const float bb = bias[gcol] * bias_scale;
#pragma unroll
        for (int m = 0; m < MF; ++m) {
            const int grow = wrow + m * 16 + lq;
#pragma unroll
            for (int q = 0; q < 4; ++q) {
                float v = acc[m][n][q] + bb;
                C[(size_t)(grow + q) * N + gcol] = v;
                if (Cb) Cb[(size_t)(grow + q) * N + gcol] = f2bf(v);
            }
        }
    }
}

__global__ __launch_bounds__(256, 2)
void gemm_pipe2_256(const u16* __restrict__ Abf, const u16* __restrict__ Bbf,
                    const float* __restrict__ bias, float bias_scale,
                    float* __restrict__ C, u16* __restrict__ Cb, int M, int N, int K) {
    gemm_pipe2_body<128, 256, 4>(Abf, Bbf, bias, bias_scale, C, Cb, M, N, K);
}

__global__ __launch_bounds__(256)
void gemm_pipe2_128(const u16* __restrict__ Abf, const u16* __restrict__ Bbf,
                    const float* __restrict__ bias, float bias_scale,
                    float* __restrict__ C, u16* __restrict__ Cb, int M, int N, int K) {
    gemm_pipe2_body<128, 128, 4>(Abf, Bbf, bias, bias_scale, C, Cb, M, N, K);
}

// ---------------------------------------------------------------------------
// fp32 fallback kernels (tiny-workspace safety net)
// ---------------------------------------------------------------------------
__global__ void embed_kernel(const int* __restrict__ tok,
                             const float* __restrict__ table,
                             const float* __restrict__ mask,
                             float* __restrict__ emb) {
    int i = blockIdx.x * blockDim.x + threadIdx.x;
    const int n4 = NB * NE / 4;
    if (i >= n4) return;
    int b = i / (NE / 4);
    int c = i % (NE / 4);
    float4 t = ((const float4*)(table + (size_t)tok[b] * NE))[c];
    float4 m = ((const float4*)mask)[i];
    float4 o;
    o.x = t.x * m.x; o.y = t.y * m.y; o.z = t.z * m.z; o.w = t.w * m.w;
    ((float4*)emb)[i] = o;
}

__global__ void lif_kernel(const float* __restrict__ delta1,
                           const float* __restrict__ hidden,
                           const float* __restrict__ mask_lif,
                           const float* __restrict__ thr_p,
                           const float* __restrict__ leak_p,
                           float* __restrict__ hsum) {
    int i = blockIdx.x * blockDim.x + threadIdx.x;
    if (i >= NB * NH) return;
    const float thr = thr_p[0];
    const float leak = leak_p[0];
    float d = delta1[i];
    float m = hidden[i];
    float cnt = 0.0f;
#pragma unroll
    for (int t = 0; t < TSTEPS; ++t) {
        float mem = leak * m + d;
        float s = ((mem / thr - 1.0f) > 0.0f) ? 1.0f : 0.0f;
        m = mem - thr * s;
        cnt += s;
    }
    hsum[i] = cnt * mask_lif[i];
}

#define BM 128
#define BN 128
#define BK 16

__global__ __launch_bounds__(256)
void gemm_nt(const float* __restrict__ A, const float* __restrict__ Bm,
             const float* __restrict__ bias, float bias_scale,
             float* __restrict__ C, int M, int N, int K) {
    __shared__ float As[BK][BM + 4];
    __shared__ float Bs[BK][BN + 4];

    const int tid = threadIdx.x;
    const int bm = blockIdx.y * BM;
    const int bn = blockIdx.x * BN;
    const int tx = tid & 15;
    const int ty = tid >> 4;
    const int tm = ty * 8;
    const int tn0 = tx * 4;
    const int tn1 = 64 + tx * 4;

    float acc[8][8];
#pragma unroll
    for (int i = 0; i < 8; ++i)
#pragma unroll
        for (int j = 0; j < 8; ++j) acc[i][j] = 0.0f;

    constexpr int LDA4 = BK / 4;

    for (int k0 = 0; k0 < K; k0 += BK) {
#pragma unroll
        for (int idx = tid; idx < BM * LDA4; idx += 256) {
            int m = idx / LDA4, c = idx % LDA4;
            float4 v = *(const float4*)(A + (size_t)(bm + m) * K + k0 + c * 4);
            As[c * 4 + 0][m] = v.x;
            As[c * 4 + 1][m] = v.y;
            As[c * 4 + 2][m] = v.z;
            As[c * 4 + 3][m] = v.w;
        }
#pragma unroll
        for (int idx = tid; idx < BN * LDA4; idx += 256) {
            int n = idx / LDA4, c = idx % LDA4;
            float4 v = make_float4(0.f, 0.f, 0.f, 0.f);
            int gn = bn + n;
            if (gn < N) v = *(const float4*)(Bm + (size_t)gn * K + k0 + c * 4);
            Bs[c * 4 + 0][n] = v.x;
            Bs[c * 4 + 1][n] = v.y;
            Bs[c * 4 + 2][n] = v.z;
            Bs[c * 4 + 3][n] = v.w;
        }
        __syncthreads();

#pragma unroll
        for (int k = 0; k < BK; ++k) {
            float4 a0 = *(const float4*)&As[k][tm];
            float4 a1 = *(const float4*)&As[k][tm + 4];
            float4 b0 = *(const float4*)&Bs[k][tn0];
            float4 b1 = *(const float4*)&Bs[k][tn1];
            float a[8] = {a0.x, a0.y, a0.z, a0.w, a1.x, a1.y, a1.z, a1.w};
            float bb[8] = {b0.x, b0.y, b0.z, b0.w, b1.x, b1.y, b1.z, b1.w};
#pragma unroll
            for (int i = 0; i < 8; ++i)
#pragma unroll
                for (int j = 0; j < 8; ++j)
                    acc[i][j] = fmaf(a[i], bb[j], acc[i][j]);
        }
        __syncthreads();
    }

#pragma unroll
    for (int i = 0; i < 8; ++i) {
        size_t row = (size_t)(bm + tm + i) * N;
#pragma unroll
        for (int j = 0; j < 8; ++j) {
            int gn = bn + ((j < 4) ? (tn0 + j) : (tn1 + j - 4));
            if (gn < N)
                C[row + gn] = acc[i][j] + bias[gn] * bias_scale;
        }
    }
}

// ---------------------------------------------------------------------------
static inline int grid1d(int N, int TBN) {
    int P = (N + TBN - 1) / TBN;
    int P8 = ((P + 7) / 8) * 8;
    return 8 * P8;                  // 8 row-blocks x padded panels
}

extern "C" void kernel_launch(void* const* d_in, const int* in_sizes, int n_in,
                              void* d_out, int out_size, void* d_ws, size_t ws_size,
                              hipStream_t stream) {
    const int*   tok      = (const int*)  d_in[0];
    const float* hidden   = (const float*)d_in[1];
    const float* table    = (const float*)d_in[2];
    const float* W1       = (const float*)d_in[3];
    const float* b1       = (const float*)d_in[4];
    const float* W2       = (const float*)d_in[5];
    const float* b2       = (const float*)d_in[6];
    const float* fc_W     = (const float*)d_in[7];
    const float* fc_b     = (const float*)d_in[8];
    const float* thr      = (const float*)d_in[9];
    const float* leak     = (const float*)d_in[10];
    const float* mask_emb = (const float*)d_in[11];
    const float* mask_lif = (const float*)d_in[12];

    float* linear = (float*)d_out;                   // [B,V]
    float* outbuf = (float*)d_out + (size_t)NB * NV; // [B,H]

    const size_t SZ_EB  = (size_t)NB * NE * 2;   // ebf
    const size_t SZ_D1  = (size_t)NB * NH * 4;   // delta1 fp32
    const size_t SZ_HB  = (size_t)NB * NH * 2;   // hbf
    const size_t SZ_OB  = (size_t)NB * NH * 2;   // obf
    const size_t SZ_W1B = (size_t)NH * NE * 2;   // W1 bf16
    const size_t SZ_W2B = (size_t)NH * NH * 2;   // W2 bf16
    const size_t SZ_WB  = (size_t)NV * NH * 2;   // fc_W bf16 (~103 MB)
    const size_t need_bf = SZ_EB + SZ_D1 + SZ_HB + SZ_OB + SZ_W1B + SZ_W2B + SZ_WB;

    char* p = (char*)d_ws;

    if (ws_size >= need_bf) {
        u16*   ebf    = (u16*)p;   p += SZ_EB;
        float* delta1 = (float*)p; p += SZ_D1;
        u16*   hbf    = (u16*)p;   p += SZ_HB;
        u16*   obf    = (u16*)p;   p += SZ_OB;
        u16*   w1b    = (u16*)p;   p += SZ_W1B;
        u16*   w2b    = (u16*)p;   p += SZ_W2B;
        u16*   fcwb   = (u16*)p;   p += SZ_WB;

        // weight converts (fc_W dominates: ~310 MB traffic, HBM-bound)
        cvt_bf16_kernel<<<2048, 256, 0, stream>>>(fc_W, fcwb, NV * NH / 4);
        cvt_bf16_kernel<<<512, 256, 0, stream>>>(W1, w1b, NH * NE / 4);
        cvt_bf16_kernel<<<512, 256, 0, stream>>>(W2, w2b, NH * NH / 4);
        // 0: embedding gather + mask -> bf16
        {
            int n4 = NB * NE / 4;
            embed_bf16_kernel<<<(n4 + 255) / 256, 256, 0, stream>>>(tok, table, mask_emb, ebf);
        }
        // 1: delta1 = ebf @ w1b^T + b1   (M=B, N=H, K=E)
        gemm_pipe2_128<<<grid1d(NH, 128), 256, 0, stream>>>(ebf, w1b, b1, 1.0f,
                                                            delta1, (u16*)nullptr, NB, NH, NE);
        // 2: LIF -> hbf (bf16)
        {
            int n = NB * NH / 4;
            lif_bf16_kernel<<<(n + 255) / 256, 256, 0, stream>>>(delta1, hidden, mask_lif,
                                                                 thr, leak, hbf);
        }
        // 3: out = hbf @ w2b^T + 10*b2 -> outbuf (fp32) + obf (bf16)
        gemm_pipe2_128<<<grid1d(NH, 128), 256, 0, stream>>>(hbf, w2b, b2, (float)TSTEPS,
                                                            outbuf, obf, NB, NH, NH);
        // 4: linear = obf @ fcwb^T + fc_b  (M=B, N=V, K=H)
        gemm_pipe2_256<<<grid1d(NV, 256), 256, 0, stream>>>(obf, fcwb, fc_b, 1.0f,
                                                            linear, (u16*)nullptr, NB, NV, NH);
    } else {
        // ----- pure fp32 fallback -----
        float* emb    = (float*)p;  p += (size_t)NB * NE * 4;
        float* delta1 = (float*)p;  p += SZ_D1;
        float* hsum   = (float*)p;

        int n4 = NB * NE / 4;
        embed_kernel<<<(n4 + 255) / 256, 256, 0, stream>>>(tok, table, mask_emb, emb);
        {
            dim3 grid(NH / BN, NB / BM);
            gemm_nt<<<grid, 256, 0, stream>>>(emb, W1, b1, 1.0f, delta1, NB, NH, NE);
        }
        {
            int n = NB * NH;
            lif_kernel<<<(n + 255) / 256, 256, 0, stream>>>(delta1, hidden, mask_lif,
                                                            thr, leak, hsum);
        }
        {
            dim3 grid(NH / BN, NB / BM);
            gemm_nt<<<grid, 256, 0, stream>>>(hsum, W2, b2, (float)TSTEPS, outbuf, NB, NH, NH);
        }
        {
            dim3 grid((NV + BN - 1) / BN, NB / BM);
            gemm_nt<<<grid, 256, 0, stream>>>(outbuf, fc_W, fc_b, 1.0f, linear, NB, NV, NH);
        }
    }
}